// Round 15
// baseline (399.788 us; speedup 1.0000x reference)
//
#include <hip/hip_runtime.h>
#include <cmath>

typedef __attribute__((ext_vector_type(8))) short bf16x8;
typedef __attribute__((ext_vector_type(4))) float f32x4;

#define MFMA16(A,B,C) __builtin_amdgcn_mfma_f32_16x16x32_bf16(A,B,C,0,0,0)

__device__ __forceinline__ ushort f2bf(float x){
  union { float f; unsigned u; } v; v.f = x;
  unsigned r = (v.u + 0x7fffu + ((v.u >> 16) & 1u)) >> 16;
  return (ushort)r;
}
__device__ __forceinline__ float bf2f(ushort h){
  union { unsigned u; float f; } v; v.u = ((unsigned)h) << 16;
  return v.f;
}

// ---------------- prep ----------------

__global__ __launch_bounds__(256) void k_cvtZ(const float* Z, ushort* AZ){
  int r = blockIdx.x, c = threadIdx.x;
  AZ[(size_t)r*512 + 256 + c] = f2bf(Z[(size_t)r*256 + c]);
}

__global__ __launch_bounds__(256) void k_transpose(const float* in, ushort* out,
                                                   int K, int N, int RS, int CO){
  __shared__ float t[32][33];
  int kb = blockIdx.x*32, nb = blockIdx.y*32;
  int tx = threadIdx.x & 31, ty = threadIdx.x >> 5;
  for (int i = ty; i < 32; i += 8){
    int k = kb + i, n = nb + tx;
    t[i][tx] = (k < K && n < N) ? in[(size_t)k*N + n] : 0.f;
  }
  __syncthreads();
  for (int i = ty; i < 32; i += 8){
    int n = nb + i, k = kb + tx;
    if (n < N && k < K) out[(size_t)n*RS + CO + k] = f2bf(t[tx][i]);
  }
}

__global__ void k_biasor(const float* bo, const float* br, float* out){
  int j = threadIdx.x;
  out[j] = bo[j] + br[j];
}

// ---------------- QKV: 16 rows/block, thread j = out col ----------------
__global__ __launch_bounds__(256) void k_qkv(
    const float* Zg, const float* Zc,
    const float* Wq, const float* bq, const float* Wk, const float* bk,
    const float* Wv, const float* bv,
    ushort* qb, ushort* kbuf, ushort* vb){
  __shared__ float zcp[16][128], zgp[16][128];
  int r0 = blockIdx.x * 16;
  int t = threadIdx.x;
  for (int i = t; i < 2048; i += 256){
    int row = i >> 7, c = i & 127;
    float vc, vg;
    if (c < 64){
      vc = Zc[(size_t)(r0+row)*64 + c];
      vg = Zg[(size_t)(r0+row)*64 + c];
    } else {
      int ii = (c - 64) >> 1;
      float div = __expf(-0.28782313662425572f * (float)ii);  // 10000^(-ii/32)
      float arg = (float)(r0 + row) * div;
      float pe = ((c - 64) & 1) ? cosf(arg) : sinf(arg);
      vc = pe; vg = pe;
    }
    zcp[row][c] = vc; zgp[row][c] = vg;
  }
  __syncthreads();
  float aq[16], ak[16], av[16];
  #pragma unroll
  for (int r = 0; r < 16; r++){ aq[r]=0.f; ak[r]=0.f; av[r]=0.f; }
  int j = t;
  #pragma unroll 4
  for (int k = 0; k < 128; k++){
    float wq = Wq[(size_t)k*256 + j];
    float wk = Wk[(size_t)k*256 + j];
    float wv = Wv[(size_t)k*256 + j];
    #pragma unroll
    for (int r = 0; r < 16; r++){
      float xc = zcp[r][k], xg = zgp[r][k];
      aq[r] = fmaf(xc, wq, aq[r]);
      ak[r] = fmaf(xg, wk, ak[r]);
      av[r] = fmaf(xg, wv, av[r]);
    }
  }
  int h = j >> 6, d = j & 63;
  float bqv = bq[j], bkv = bk[j], bvv = bv[j];
  #pragma unroll
  for (int r = 0; r < 16; r++){
    size_t base = ((size_t)h*4096 + (r0 + r))*64 + d;
    qb[base]   = f2bf((aq[r] + bqv) * 0.125f);  // fold 1/sqrt(64)
    kbuf[base] = f2bf(ak[r] + bkv);
    vb[base]   = f2bf(av[r] + bvv);
  }
}

// vb [h][4096][64] -> vtb [h][64][4096]
__global__ __launch_bounds__(256) void k_vtrans(const ushort* vb, ushort* vtb){
  __shared__ ushort t[64][65];
  int h = blockIdx.y, n0 = blockIdx.x * 64;
  int tx = threadIdx.x & 63, ty = threadIdx.x >> 6;
  for (int i = ty; i < 64; i += 4)
    t[i][tx] = vb[((size_t)h*4096 + n0 + i)*64 + tx];
  __syncthreads();
  for (int i = ty; i < 64; i += 4)
    vtb[((size_t)h*64 + i)*4096 + n0 + tx] = t[tx][i];
}

// ---------------- fused attention: single pass, 8-row strips, 2 blocks/CU ----------------
// block = (head, 8-row strip) XCD-swizzled, 512 threads = 8 waves, 64KB LDS
// -> 2 blocks/CU so one block's store burst overlaps the other's compute.
// Phase 1 (no barriers): QK^T+exp once; rowsum in regs (lanes lg<2 own the 8
//   rows); unnormalized bf16 P into swizzled LDS. Phase 2: rowsum reduce.
//   Phase 3: normalized f32 NT stores (wave sweeps one 16KB row). Phase 4: PV
//   from LDS (wave owns 512-k slice). Phase 5: reduce (aliases pbf) -> AZ.
__global__ __launch_bounds__(512, 4) void k_attn4(
    const ushort* qb, const ushort* kbuf, const ushort* vtb,
    const float* adj, float* attn_out, ushort* az){
  __shared__ __align__(16) char smem[8*4096*2];    // 64 KB: pbf / pvp alias
  __shared__ float red[8][8];
  __shared__ float rsl[8];
  ushort* pbf = (ushort*)smem;                     // [8][4096], XOR-swizzled
  float (*pvp)[8][66] = (float(*)[8][66])smem;     // [8waves][8rows][64d+pad]

  // XCD-bijective swizzle (2048 = 8 x 256): 64 strips x 4 heads per XCD
  int bid = blockIdx.x;
  int xcd = bid & 7, slot = bid >> 3;
  int nb = xcd*64 + (slot >> 2);                   // 8-row strip index 0..511
  int h  = slot & 3;
  int n0 = nb * 8;

  int t = threadIdx.x;
  int wave = t >> 6, lane = t & 63, lr = lane & 15, lg = lane >> 4;

  const ushort* Qh = qb   + ((size_t)h*4096 + n0)*64;
  const ushort* Kh = kbuf + (size_t)h*4096*64;
  const ushort* Vt = vtb  + (size_t)h*64*4096;
  float* aout = attn_out + (size_t)h*4096*4096 + (size_t)n0*4096;

  // A-frag: rows lr (rows 8..15 duplicate rows 0..7; their outputs unused)
  bf16x8 afr0 = *(const bf16x8*)(Qh + (size_t)(lr & 7)*64 +  0 + lg*8);
  bf16x8 afr1 = *(const bf16x8*)(Qh + (size_t)(lr & 7)*64 + 32 + lg*8);

  // ---- phase 1: QK^T + exp + rowsum + P->LDS (no barriers) ----
  float rsum[4] = {0.f, 0.f, 0.f, 0.f};
  #pragma unroll 2
  for (int ct = 0; ct < 32; ct++){
    int cw = ct*128 + wave*16;                 // this wave's 16 cols
    const ushort* kp = Kh + (size_t)(cw + lr)*64 + lg*8;
    bf16x8 b0 = *(const bf16x8*)(kp);
    bf16x8 b1 = *(const bf16x8*)(kp + 32);
    f32x4 acc = {0.f, 0.f, 0.f, 0.f};
    acc = MFMA16(afr0, b0, acc);
    acc = MFMA16(afr1, b1, acc);
    if (lg < 2){                               // rows lg*4+r in 0..7 (valid)
      const float* ap = adj + (size_t)(n0 + lg*4)*4096 + cw + lr;
      float a0 = ap[0], a1 = ap[4096], a2 = ap[8192], a3 = ap[12288];
      float p0 = a0 * __expf(acc[0]);
      float p1 = a1 * __expf(acc[1]);
      float p2 = a2 * __expf(acc[2]);
      float p3 = a3 * __expf(acc[3]);
      rsum[0] += p0; rsum[1] += p1; rsum[2] += p2; rsum[3] += p3;
      int col = cw + lr;
      float p4[4] = {p0, p1, p2, p3};
      #pragma unroll
      for (int r = 0; r < 4; r++){
        int row = lg*4 + r;
        pbf[row*4096 + (col ^ ((row & 7) << 3))] = f2bf(p4[r]);
      }
    }
  }
  #pragma unroll
  for (int m = 1; m <= 8; m <<= 1){
    #pragma unroll
    for (int r = 0; r < 4; r++) rsum[r] += __shfl_xor(rsum[r], m, 64);
  }
  if (lr == 0 && lg < 2){
    #pragma unroll
    for (int r = 0; r < 4; r++) red[wave][lg*4 + r] = rsum[r];
  }
  __syncthreads();
  if (t < 8){
    float s = 0.f;
    #pragma unroll
    for (int w2 = 0; w2 < 8; w2++) s += red[w2][t];
    rsl[t] = 1.f / s;
  }
  __syncthreads();

  // ---- phase 3: normalized attn stores (wave sweeps row `wave`) ----
  {
    int row = wave;                            // 0..7
    float iv = rsl[row];
    int swz = (row & 7) << 3;
    #pragma unroll 2
    for (int q = 0; q < 16; q++){
      int c = q*256 + lane*4;
      const ushort* src = &pbf[row*4096 + (c ^ swz)];
      ushort s4[4];
      *(uint2*)s4 = *(const uint2*)src;
      f32x4 ov = {bf2f(s4[0])*iv, bf2f(s4[1])*iv, bf2f(s4[2])*iv, bf2f(s4[3])*iv};
      __builtin_nontemporal_store(ov, (f32x4*)(aout + (size_t)row*4096 + c));
    }
  }

  // ---- phase 4: PV from LDS (wave owns k-slice [wave*512, wave*512+512)) ----
  f32x4 pacc[4];
  #pragma unroll
  for (int d = 0; d < 4; d++) pacc[d] = (f32x4){0.f,0.f,0.f,0.f};
  #pragma unroll 2
  for (int ks = 0; ks < 16; ks++){
    int kb2 = wave*512 + ks*32;
    // A rows = lr; rows 8..15 read duplicate P rows (outputs unused)
    bf16x8 pa = *(const bf16x8*)&pbf[(lr & 7)*4096 + ((kb2 + lg*8) ^ ((lr & 7) << 3))];
    #pragma unroll
    for (int df = 0; df < 4; df++){
      bf16x8 v8 = *(const bf16x8*)(Vt + (size_t)(df*16 + lr)*4096 + kb2 + lg*8);
      pacc[df] = MFMA16(pa, v8, pacc[df]);
    }
  }

  // ---- phase 5: cross-wave PV reduce (pvp aliases pbf) -> AZ ----
  __syncthreads();                              // all pbf reads done
  if (lg < 2){
    #pragma unroll
    for (int df = 0; df < 4; df++)
      #pragma unroll
      for (int r = 0; r < 4; r++)
        pvp[wave][lg*4 + r][df*16 + lr] = pacc[df][r];
  }
  __syncthreads();
  {
    int row = t >> 6;                           // 8 rows x 64 d = 512 threads
    int d   = t & 63;
    float s = 0.f;
    #pragma unroll
    for (int w2 = 0; w2 < 8; w2++) s += pvp[w2][row][d];
    s *= rsl[row];                              // normalize PV
    az[(size_t)(n0 + row)*512 + h*64 + d] = f2bf(s);
  }
}

// ---------------- generic GEMM: C = act(A @ Bt^T + bias [+ res]) ----------------
__global__ __launch_bounds__(256) void k_gemm(
    const ushort* A, const ushort* Bt, const float* bias,
    const float* res, float* outf, ushort* outb,
    int M, int N, int K, int mode){
  __shared__ __align__(16) ushort la[64][40];
  __shared__ __align__(16) ushort lb[64][40];
  int mb = blockIdx.x * 64, nb = blockIdx.y * 64;
  int t = threadIdx.x;
  int wave = t >> 6, lane = t & 63, lr = lane & 15, lg = lane >> 4;
  int wm = (wave >> 1) * 32, wn = (wave & 1) * 32;
  f32x4 acc[2][2];
  #pragma unroll
  for (int i = 0; i < 2; i++)
    #pragma unroll
    for (int j = 0; j < 2; j++) acc[i][j] = (f32x4){0.f,0.f,0.f,0.f};

  int srow = t >> 2, scol = (t & 3) * 8;
  for (int k0 = 0; k0 < K; k0 += 32){
    *(bf16x8*)&la[srow][scol] = *(const bf16x8*)(A  + (size_t)(mb+srow)*K + k0 + scol);
    *(bf16x8*)&lb[srow][scol] = *(const bf16x8*)(Bt + (size_t)(nb+srow)*K + k0 + scol);
    __syncthreads();
    #pragma unroll
    for (int i = 0; i < 2; i++){
      bf16x8 af = *(const bf16x8*)&la[wm + i*16 + lr][lg*8];
      #pragma unroll
      for (int j = 0; j < 2; j++){
        bf16x8 bfg = *(const bf16x8*)&lb[wn + j*16 + lr][lg*8];
        acc[i][j] = MFMA16(af, bfg, acc[i][j]);
      }
    }
    __syncthreads();
  }

  #pragma unroll
  for (int i = 0; i < 2; i++)
    #pragma unroll
    for (int j = 0; j < 2; j++){
      int col = nb + wn + j*16 + lr;
      float bv = bias[col];
      #pragma unroll
      for (int r = 0; r < 4; r++){
        int row = mb + wm + i*16 + lg*4 + r;
        float v = acc[i][j][r] + bv;
        if (mode == 0){
          if (res) v += res[(size_t)row*N + col];
          outf[(size_t)row*N + col] = v;
        } else {
          float gl = 0.5f * v * (1.f + erff(v * 0.70710678118f));
          outb[(size_t)row*N + col] = f2bf(gl);
        }
      }
    }
}

// ---------------- LayerNorm over 256 cols, wave per row ----------------
__global__ __launch_bounds__(256) void k_ln(const float* X, const float* g, const float* b,
                                            float* outf, ushort* outb){
  int row = blockIdx.x * 4 + (threadIdx.x >> 6);
  int lane = threadIdx.x & 63;
  const float* xr = X + (size_t)row*256;
  f32x4 v = *(const f32x4*)(xr + lane*4);
  float s = v[0] + v[1] + v[2] + v[3];
  #pragma unroll
  for (int m = 32; m >= 1; m >>= 1) s += __shfl_xor(s, m, 64);
  float mean = s * (1.f/256.f);
  float d0[4]; float sq = 0.f;
  #pragma unroll
  for (int e = 0; e < 4; e++){ d0[e] = v[e] - mean; sq += d0[e]*d0[e]; }
  #pragma unroll
  for (int m = 32; m >= 1; m >>= 1) sq += __shfl_xor(sq, m, 64);
  float rstd = rsqrtf(sq * (1.f/256.f) + 1e-5f);
  float o[4];
  #pragma unroll
  for (int e = 0; e < 4; e++)
    o[e] = d0[e]*rstd*g[lane*4 + e] + b[lane*4 + e];
  if (outf){
    f32x4 ov = {o[0], o[1], o[2], o[3]};
    *(f32x4*)(outf + (size_t)row*256 + lane*4) = ov;
  }
  if (outb){
    union { ushort u[4]; uint2 q; } pk;
    #pragma unroll
    for (int e = 0; e < 4; e++) pk.u[e] = f2bf(o[e]);
    *(uint2*)(outb + (size_t)row*256 + lane*4) = pk.q;
  }
}

// ---------------- launch ----------------
extern "C" void kernel_launch(void* const* d_in, const int* in_sizes, int n_in,
                              void* d_out, int out_size, void* d_ws, size_t ws_size,
                              hipStream_t stream){
  const float* Z    = (const float*)d_in[0];
  const float* Zg   = (const float*)d_in[1];
  const float* Zc   = (const float*)d_in[2];
  const float* adj  = (const float*)d_in[3];
  const float* Wq   = (const float*)d_in[4];
  const float* bq   = (const float*)d_in[5];
  const float* Wk   = (const float*)d_in[6];
  const float* bk   = (const float*)d_in[7];
  const float* Wv   = (const float*)d_in[8];
  const float* bv   = (const float*)d_in[9];
  const float* Wo   = (const float*)d_in[10];
  const float* bo   = (const float*)d_in[11];
  const float* Wr   = (const float*)d_in[12];
  const float* br   = (const float*)d_in[13];
  const float* ln1g = (const float*)d_in[14];
  const float* ln1b = (const float*)d_in[15];
  const float* ln2g = (const float*)d_in[16];
  const float* ln2b = (const float*)d_in[17];
  const float* f1w  = (const float*)d_in[18];
  const float* f1b  = (const float*)d_in[19];
  const float* f2w  = (const float*)d_in[20];
  const float* f2b  = (const float*)d_in[21];
  const float* f3w  = (const float*)d_in[22];
  const float* f3b  = (const float*)d_in[23];

  // OUTPUTS: f32 out [4096*256] then f32 attn [4*4096*4096]
  float* outF  = (float*)d_out;
  float* attnF = outF + (size_t)4096*256;

  const size_t MB = 1048576;
  char* w = (char*)d_ws;
  ushort* qb    = (ushort*)(w + 0*MB);      // 2 MB, dead after k_attn4
  ushort* kbuf  = (ushort*)(w + 2*MB);      // 2 MB, dead after k_attn4
  ushort* vtb   = (ushort*)(w + 4*MB);      // 2 MB, dead after k_attn4
  ushort* vb    = (ushort*)(w + 6*MB);      // 2 MB, dead after k_vtrans
  ushort* h1    = (ushort*)(w + 0*MB);      // 8 MB, written after k_attn4
  ushort* AZ    = (ushort*)(w + 8*MB);      // 4 MB, dead after gemm1
  ushort* h2    = (ushort*)(w + 8*MB);      // 4 MB, written after gemm1
  ushort* BoR   = (ushort*)(w + 12*MB);                 // 256 KB [256][512]
  float*  biasOR= (float*)(w + 12*MB + 262144);         // 1 KB
  ushort* f1T   = (ushort*)(w + 13*MB);     // 512 KB [1024][256]
  ushort* f2T   = (ushort*)(w + 13*MB + 524288);  // 1 MB [512][1024]
  ushort* f3T   = (ushort*)(w + 14*MB + 524288);  // 256 KB [256][512]
  float*  X1    = (float*)(w + 15*MB);      // 4 MB
  float*  yf    = (float*)(w + 19*MB);      // 4 MB
  ushort* yb    = (ushort*)(w + 23*MB);     // 2 MB -> peak 25 MB

  // prep
  k_cvtZ<<<4096, 256, 0, stream>>>(Z, AZ);
  k_transpose<<<dim3(8,  8), 256, 0, stream>>>(Wo,  BoR,  256,  256, 512,   0);
  k_transpose<<<dim3(8,  8), 256, 0, stream>>>(Wr,  BoR,  256,  256, 512, 256);
  k_transpose<<<dim3(8, 32), 256, 0, stream>>>(f1w, f1T,  256, 1024, 256,   0);
  k_transpose<<<dim3(32,16), 256, 0, stream>>>(f2w, f2T, 1024,  512, 1024,  0);
  k_transpose<<<dim3(16, 8), 256, 0, stream>>>(f3w, f3T,  512,  256, 512,   0);
  k_biasor<<<1, 256, 0, stream>>>(bo, br, biasOR);

  // QKV + V transpose
  k_qkv<<<256, 256, 0, stream>>>(Zg, Zc, Wq, bq, Wk, bk, Wv, bv, qb, kbuf, vb);
  k_vtrans<<<dim3(64, 4), 256, 0, stream>>>(vb, vtb);

  // fused attention (single pass, 2 blocks/CU): attn (f32, NT) + AZ (bf16)
  k_attn4<<<2048, 512, 0, stream>>>(qb, kbuf, vtb, adj, attnF, AZ);

  // X1 = [attended|Z] @ [Wo;Wr]^T + (bo+br)
  k_gemm<<<dim3(64, 4), 256, 0, stream>>>(AZ, BoR, biasOR, nullptr, X1, nullptr,
                                          4096, 256, 512, 0);
  k_ln<<<1024, 256, 0, stream>>>(X1, ln1g, ln1b, yf, yb);

  // FFN
  k_gemm<<<dim3(64,16), 256, 0, stream>>>(yb, f1T, f1b, nullptr, nullptr, h1,
                                          4096, 1024, 256, 1);
  k_gemm<<<dim3(64, 8), 256, 0, stream>>>(h1, f2T, f2b, nullptr, nullptr, h2,
                                          4096, 512, 1024, 1);
  k_gemm<<<dim3(64, 4), 256, 0, stream>>>(h2, f3T, f3b, yf, X1, nullptr,
                                          4096, 256, 512, 0);
  k_ln<<<1024, 256, 0, stream>>>(X1, ln2g, ln2b, outF, nullptr);
}

// Round 16
// 302.544 us; speedup vs baseline: 1.3214x; 1.3214x over previous
//
#include <hip/hip_runtime.h>
#include <cmath>

typedef __attribute__((ext_vector_type(8))) short bf16x8;
typedef __attribute__((ext_vector_type(4))) float f32x4;

#define MFMA16(A,B,C) __builtin_amdgcn_mfma_f32_16x16x32_bf16(A,B,C,0,0,0)

__device__ __forceinline__ ushort f2bf(float x){
  union { float f; unsigned u; } v; v.f = x;
  unsigned r = (v.u + 0x7fffu + ((v.u >> 16) & 1u)) >> 16;
  return (ushort)r;
}
__device__ __forceinline__ float bf2f(ushort h){
  union { unsigned u; float f; } v; v.u = ((unsigned)h) << 16;
  return v.f;
}

// ---------------- prep ----------------

__global__ __launch_bounds__(256) void k_cvtZ(const float* Z, ushort* AZ){
  int r = blockIdx.x, c = threadIdx.x;
  AZ[(size_t)r*512 + 256 + c] = f2bf(Z[(size_t)r*256 + c]);
}

__global__ __launch_bounds__(256) void k_transpose(const float* in, ushort* out,
                                                   int K, int N, int RS, int CO){
  __shared__ float t[32][33];
  int kb = blockIdx.x*32, nb = blockIdx.y*32;
  int tx = threadIdx.x & 31, ty = threadIdx.x >> 5;
  for (int i = ty; i < 32; i += 8){
    int k = kb + i, n = nb + tx;
    t[i][tx] = (k < K && n < N) ? in[(size_t)k*N + n] : 0.f;
  }
  __syncthreads();
  for (int i = ty; i < 32; i += 8){
    int n = nb + i, k = kb + tx;
    if (n < N && k < K) out[(size_t)n*RS + CO + k] = f2bf(t[tx][i]);
  }
}

__global__ void k_biasor(const float* bo, const float* br, float* out){
  int j = threadIdx.x;
  out[j] = bo[j] + br[j];
}

// ---------------- QKV: 16 rows/block, thread j = out col ----------------
__global__ __launch_bounds__(256) void k_qkv(
    const float* Zg, const float* Zc,
    const float* Wq, const float* bq, const float* Wk, const float* bk,
    const float* Wv, const float* bv,
    ushort* qb, ushort* kbuf, ushort* vb){
  __shared__ float zcp[16][128], zgp[16][128];
  int r0 = blockIdx.x * 16;
  int t = threadIdx.x;
  for (int i = t; i < 2048; i += 256){
    int row = i >> 7, c = i & 127;
    float vc, vg;
    if (c < 64){
      vc = Zc[(size_t)(r0+row)*64 + c];
      vg = Zg[(size_t)(r0+row)*64 + c];
    } else {
      int ii = (c - 64) >> 1;
      float div = __expf(-0.28782313662425572f * (float)ii);  // 10000^(-ii/32)
      float arg = (float)(r0 + row) * div;
      float pe = ((c - 64) & 1) ? cosf(arg) : sinf(arg);
      vc = pe; vg = pe;
    }
    zcp[row][c] = vc; zgp[row][c] = vg;
  }
  __syncthreads();
  float aq[16], ak[16], av[16];
  #pragma unroll
  for (int r = 0; r < 16; r++){ aq[r]=0.f; ak[r]=0.f; av[r]=0.f; }
  int j = t;
  #pragma unroll 4
  for (int k = 0; k < 128; k++){
    float wq = Wq[(size_t)k*256 + j];
    float wk = Wk[(size_t)k*256 + j];
    float wv = Wv[(size_t)k*256 + j];
    #pragma unroll
    for (int r = 0; r < 16; r++){
      float xc = zcp[r][k], xg = zgp[r][k];
      aq[r] = fmaf(xc, wq, aq[r]);
      ak[r] = fmaf(xg, wk, ak[r]);
      av[r] = fmaf(xg, wv, av[r]);
    }
  }
  int h = j >> 6, d = j & 63;
  float bqv = bq[j], bkv = bk[j], bvv = bv[j];
  #pragma unroll
  for (int r = 0; r < 16; r++){
    size_t base = ((size_t)h*4096 + (r0 + r))*64 + d;
    qb[base]   = f2bf((aq[r] + bqv) * 0.125f);  // fold 1/sqrt(64)
    kbuf[base] = f2bf(ak[r] + bkv);
    vb[base]   = f2bf(av[r] + bvv);
  }
}

// vb [h][4096][64] -> vtb [h][64][4096]
__global__ __launch_bounds__(256) void k_vtrans(const ushort* vb, ushort* vtb){
  __shared__ ushort t[64][65];
  int h = blockIdx.y, n0 = blockIdx.x * 64;
  int tx = threadIdx.x & 63, ty = threadIdx.x >> 6;
  for (int i = ty; i < 64; i += 4)
    t[i][tx] = vb[((size_t)h*4096 + n0 + i)*64 + tx];
  __syncthreads();
  for (int i = ty; i < 64; i += 4)
    vtb[((size_t)h*64 + i)*4096 + n0 + tx] = t[tx][i];
}

// ---------------- fused attention: SINGLE PASS, full P tile in LDS (R14, proven) ----------------
__global__ __launch_bounds__(1024, 4) void k_attn3(
    const ushort* qb, const ushort* kbuf, const ushort* vtb,
    const float* adj, float* attn_out, ushort* az){
  __shared__ __align__(16) char smem[16*4096*2];   // 128 KB: pbf / pvp alias
  __shared__ float red[16][16];
  __shared__ float rsl[16];
  ushort* pbf = (ushort*)smem;                     // [16][4096], XOR-swizzled
  float (*pvp)[16][66] = (float(*)[16][66])smem;   // [16waves][16rows][64d+pad]

  int bid = blockIdx.x;
  int xcd = bid & 7, slot = bid >> 3;
  int nb = xcd*32 + (slot >> 2);
  int h  = slot & 3;
  int n0 = nb * 16;

  int t = threadIdx.x;
  int wave = t >> 6, lane = t & 63, lr = lane & 15, lg = lane >> 4;

  const ushort* Qh = qb   + ((size_t)h*4096 + n0)*64;
  const ushort* Kh = kbuf + (size_t)h*4096*64;
  const ushort* Vt = vtb  + (size_t)h*64*4096;
  float* aout = attn_out + (size_t)h*4096*4096 + (size_t)n0*4096;

  bf16x8 afr0 = *(const bf16x8*)(Qh + (size_t)lr*64 +  0 + lg*8);
  bf16x8 afr1 = *(const bf16x8*)(Qh + (size_t)lr*64 + 32 + lg*8);

  // ---- phase 1: QK^T + exp + rowsum + P->LDS (no barriers) ----
  float rsum[4] = {0.f, 0.f, 0.f, 0.f};
  #pragma unroll 2
  for (int ct = 0; ct < 16; ct++){
    int cw = ct*256 + wave*16;
    const ushort* kp = Kh + (size_t)(cw + lr)*64 + lg*8;
    bf16x8 b0 = *(const bf16x8*)(kp);
    bf16x8 b1 = *(const bf16x8*)(kp + 32);
    const float* ap = adj + (size_t)(n0 + lg*4)*4096 + cw + lr;
    float a0 = ap[0], a1 = ap[4096], a2 = ap[8192], a3 = ap[12288];
    f32x4 acc = {0.f, 0.f, 0.f, 0.f};
    acc = MFMA16(afr0, b0, acc);
    acc = MFMA16(afr1, b1, acc);
    float p0 = a0 * __expf(acc[0]);
    float p1 = a1 * __expf(acc[1]);
    float p2 = a2 * __expf(acc[2]);
    float p3 = a3 * __expf(acc[3]);
    rsum[0] += p0; rsum[1] += p1; rsum[2] += p2; rsum[3] += p3;
    int col = cw + lr;
    float p4[4] = {p0, p1, p2, p3};
    #pragma unroll
    for (int r = 0; r < 4; r++){
      int row = lg*4 + r;
      pbf[row*4096 + (col ^ ((row & 7) << 3))] = f2bf(p4[r]);
    }
  }
  #pragma unroll
  for (int m = 1; m <= 8; m <<= 1){
    #pragma unroll
    for (int r = 0; r < 4; r++) rsum[r] += __shfl_xor(rsum[r], m, 64);
  }
  if (lr == 0){
    #pragma unroll
    for (int r = 0; r < 4; r++) red[wave][lg*4 + r] = rsum[r];
  }
  __syncthreads();
  if (t < 16){
    float s = 0.f;
    #pragma unroll
    for (int w2 = 0; w2 < 16; w2++) s += red[w2][t];
    rsl[t] = 1.f / s;
  }
  __syncthreads();

  // ---- phase 3: normalized attn stores (wave sweeps row `wave`) ----
  {
    int row = wave;
    float iv = rsl[row];
    int swz = (row & 7) << 3;
    #pragma unroll 2
    for (int q = 0; q < 16; q++){
      int c = q*256 + lane*4;
      const ushort* src = &pbf[row*4096 + (c ^ swz)];
      ushort s4[4];
      *(uint2*)s4 = *(const uint2*)src;
      f32x4 ov = {bf2f(s4[0])*iv, bf2f(s4[1])*iv, bf2f(s4[2])*iv, bf2f(s4[3])*iv};
      __builtin_nontemporal_store(ov, (f32x4*)(aout + (size_t)row*4096 + c));
    }
  }

  // ---- phase 4: PV from LDS (wave owns k-slice [wave*256, wave*256+256)) ----
  f32x4 pacc[4];
  #pragma unroll
  for (int d = 0; d < 4; d++) pacc[d] = (f32x4){0.f,0.f,0.f,0.f};
  #pragma unroll
  for (int ks = 0; ks < 8; ks++){
    int kb2 = wave*256 + ks*32;
    bf16x8 pa = *(const bf16x8*)&pbf[lr*4096 + ((kb2 + lg*8) ^ ((lr & 7) << 3))];
    #pragma unroll
    for (int df = 0; df < 4; df++){
      bf16x8 v8 = *(const bf16x8*)(Vt + (size_t)(df*16 + lr)*4096 + kb2 + lg*8);
      pacc[df] = MFMA16(pa, v8, pacc[df]);
    }
  }

  // ---- phase 5: cross-wave PV reduce (pvp aliases pbf) -> AZ ----
  __syncthreads();
  #pragma unroll
  for (int df = 0; df < 4; df++)
    #pragma unroll
    for (int r = 0; r < 4; r++)
      pvp[wave][lg*4 + r][df*16 + lr] = pacc[df][r];
  __syncthreads();
  {
    int row = t >> 6;
    int d   = t & 63;
    float s = 0.f;
    #pragma unroll
    for (int w2 = 0; w2 < 16; w2++) s += pvp[w2][row][d];
    s *= rsl[row];
    az[(size_t)(n0 + row)*512 + h*64 + d] = f2bf(s);
  }
}

// ---------------- generic GEMM: C = act(A @ Bt^T + bias) (gelu->bf16 or f32) ----------------
__global__ __launch_bounds__(256) void k_gemm(
    const ushort* A, const ushort* Bt, const float* bias,
    const float* res, float* outf, ushort* outb,
    int M, int N, int K, int mode){
  __shared__ __align__(16) ushort la[64][40];
  __shared__ __align__(16) ushort lb[64][40];
  int mb = blockIdx.x * 64, nb = blockIdx.y * 64;
  int t = threadIdx.x;
  int wave = t >> 6, lane = t & 63, lr = lane & 15, lg = lane >> 4;
  int wm = (wave >> 1) * 32, wn = (wave & 1) * 32;
  f32x4 acc[2][2];
  #pragma unroll
  for (int i = 0; i < 2; i++)
    #pragma unroll
    for (int j = 0; j < 2; j++) acc[i][j] = (f32x4){0.f,0.f,0.f,0.f};

  int srow = t >> 2, scol = (t & 3) * 8;
  for (int k0 = 0; k0 < K; k0 += 32){
    *(bf16x8*)&la[srow][scol] = *(const bf16x8*)(A  + (size_t)(mb+srow)*K + k0 + scol);
    *(bf16x8*)&lb[srow][scol] = *(const bf16x8*)(Bt + (size_t)(nb+srow)*K + k0 + scol);
    __syncthreads();
    #pragma unroll
    for (int i = 0; i < 2; i++){
      bf16x8 af = *(const bf16x8*)&la[wm + i*16 + lr][lg*8];
      #pragma unroll
      for (int j = 0; j < 2; j++){
        bf16x8 bfg = *(const bf16x8*)&lb[wn + j*16 + lr][lg*8];
        acc[i][j] = MFMA16(af, bfg, acc[i][j]);
      }
    }
    __syncthreads();
  }

  #pragma unroll
  for (int i = 0; i < 2; i++)
    #pragma unroll
    for (int j = 0; j < 2; j++){
      int col = nb + wn + j*16 + lr;
      float bv = bias[col];
      #pragma unroll
      for (int r = 0; r < 4; r++){
        int row = mb + wm + i*16 + lg*4 + r;
        float v = acc[i][j][r] + bv;
        if (mode == 0){
          if (res) v += res[(size_t)row*N + col];
          outf[(size_t)row*N + col] = v;
        } else {
          float gl = 0.5f * v * (1.f + erff(v * 0.70710678118f));
          outb[(size_t)row*N + col] = f2bf(gl);
        }
      }
    }
}

// ---------------- fused GEMM + LayerNorm: 32 rows x 256 cols (full width) ----------------
// X = A @ Bt^T + bias (+res); LN over the 256 cols; write outf (f32) / outb (bf16).
// 256 threads = 4 waves; wave w owns cols w*64..w*64+63; acc[2][4] per thread.
__global__ __launch_bounds__(256) void k_gemm_ln(
    const ushort* A, const ushort* Bt, const float* bias, const float* res,
    const float* g, const float* b, float* outf, ushort* outb, int K){
  __shared__ __align__(16) ushort la[32][40];
  __shared__ __align__(16) ushort lb[256][40];
  __shared__ float rsm[32][5];
  __shared__ float rsq[32][5];
  int mb = blockIdx.x * 32;
  int t = threadIdx.x;
  int wave = t >> 6, lane = t & 63, lr = lane & 15, lg = lane >> 4;

  f32x4 acc[2][4];
  #pragma unroll
  for (int i = 0; i < 2; i++)
    #pragma unroll
    for (int j = 0; j < 4; j++) acc[i][j] = (f32x4){0.f,0.f,0.f,0.f};

  int sr = t >> 2, sc = (t & 3) * 8;      // B staging: 4 rows/thread
  for (int k0 = 0; k0 < K; k0 += 32){
    if (t < 128)
      *(bf16x8*)&la[sr][sc] = *(const bf16x8*)(A + (size_t)(mb+sr)*K + k0 + sc);
    #pragma unroll
    for (int q = 0; q < 4; q++)
      *(bf16x8*)&lb[sr + 64*q][sc] = *(const bf16x8*)(Bt + (size_t)(sr+64*q)*K + k0 + sc);
    __syncthreads();
    #pragma unroll
    for (int i = 0; i < 2; i++){
      bf16x8 af = *(const bf16x8*)&la[i*16 + lr][lg*8];
      #pragma unroll
      for (int j = 0; j < 4; j++){
        bf16x8 bfg = *(const bf16x8*)&lb[wave*64 + j*16 + lr][lg*8];
        acc[i][j] = MFMA16(af, bfg, acc[i][j]);
      }
    }
    __syncthreads();
  }

  // add bias (+res); accumulate per-row partial sum / sumsq
  float v[2][4][4];
  #pragma unroll
  for (int i = 0; i < 2; i++)
    #pragma unroll
    for (int r = 0; r < 4; r++){
      int row = mb + i*16 + lg*4 + r;
      float s = 0.f, q = 0.f;
      #pragma unroll
      for (int j = 0; j < 4; j++){
        int col = wave*64 + j*16 + lr;
        float x = acc[i][j][r] + bias[col];
        if (res) x += res[(size_t)row*256 + col];
        v[i][j][r] = x;
        s += x; q += x*x;
      }
      // reduce over lr lanes (bits 0..3)
      #pragma unroll
      for (int m = 1; m <= 8; m <<= 1){
        s += __shfl_xor(s, m, 64);
        q += __shfl_xor(q, m, 64);
      }
      if (lr == 0){
        rsm[i*16 + lg*4 + r][wave] = s;
        rsq[i*16 + lg*4 + r][wave] = q;
      }
    }
  __syncthreads();

  #pragma unroll
  for (int i = 0; i < 2; i++)
    #pragma unroll
    for (int r = 0; r < 4; r++){
      int rl = i*16 + lg*4 + r;
      float tot  = rsm[rl][0] + rsm[rl][1] + rsm[rl][2] + rsm[rl][3];
      float totq = rsq[rl][0] + rsq[rl][1] + rsq[rl][2] + rsq[rl][3];
      float mean = tot * (1.f/256.f);
      float var  = totq * (1.f/256.f) - mean*mean;
      float rstd = rsqrtf(var + 1e-5f);
      int row = mb + rl;
      #pragma unroll
      for (int j = 0; j < 4; j++){
        int col = wave*64 + j*16 + lr;
        float o = (v[i][j][r] - mean)*rstd*g[col] + b[col];
        if (outf) outf[(size_t)row*256 + col] = o;
        if (outb) outb[(size_t)row*256 + col] = f2bf(o);
      }
    }
}

// ---------------- launch ----------------
extern "C" void kernel_launch(void* const* d_in, const int* in_sizes, int n_in,
                              void* d_out, int out_size, void* d_ws, size_t ws_size,
                              hipStream_t stream){
  const float* Z    = (const float*)d_in[0];
  const float* Zg   = (const float*)d_in[1];
  const float* Zc   = (const float*)d_in[2];
  const float* adj  = (const float*)d_in[3];
  const float* Wq   = (const float*)d_in[4];
  const float* bq   = (const float*)d_in[5];
  const float* Wk   = (const float*)d_in[6];
  const float* bk   = (const float*)d_in[7];
  const float* Wv   = (const float*)d_in[8];
  const float* bv   = (const float*)d_in[9];
  const float* Wo   = (const float*)d_in[10];
  const float* bo   = (const float*)d_in[11];
  const float* Wr   = (const float*)d_in[12];
  const float* br   = (const float*)d_in[13];
  const float* ln1g = (const float*)d_in[14];
  const float* ln1b = (const float*)d_in[15];
  const float* ln2g = (const float*)d_in[16];
  const float* ln2b = (const float*)d_in[17];
  const float* f1w  = (const float*)d_in[18];
  const float* f1b  = (const float*)d_in[19];
  const float* f2w  = (const float*)d_in[20];
  const float* f2b  = (const float*)d_in[21];
  const float* f3w  = (const float*)d_in[22];
  const float* f3b  = (const float*)d_in[23];

  // OUTPUTS: f32 out [4096*256] then f32 attn [4*4096*4096]
  float* outF  = (float*)d_out;
  float* attnF = outF + (size_t)4096*256;

  const size_t MB = 1048576;
  char* w = (char*)d_ws;
  ushort* qb    = (ushort*)(w + 0*MB);      // 2 MB, dead after k_attn3
  ushort* kbuf  = (ushort*)(w + 2*MB);      // 2 MB, dead after k_attn3
  ushort* vtb   = (ushort*)(w + 4*MB);      // 2 MB, dead after k_attn3
  ushort* vb    = (ushort*)(w + 6*MB);      // 2 MB, dead after k_vtrans
  ushort* h1    = (ushort*)(w + 0*MB);      // 8 MB, written after k_attn3
  ushort* AZ    = (ushort*)(w + 8*MB);      // 4 MB, dead after gemm1
  ushort* h2    = (ushort*)(w + 8*MB);      // 4 MB, written after gemm1
  ushort* BoR   = (ushort*)(w + 12*MB);                 // 256 KB [256][512]
  float*  biasOR= (float*)(w + 12*MB + 262144);         // 1 KB
  ushort* f1T   = (ushort*)(w + 13*MB);     // 512 KB [1024][256]
  ushort* f2T   = (ushort*)(w + 13*MB + 524288);  // 1 MB [512][1024]
  ushort* f3T   = (ushort*)(w + 14*MB + 524288);  // 256 KB [256][512]
  float*  yf    = (float*)(w + 15*MB);      // 4 MB (LN1 out, residual for f3)
  ushort* yb    = (ushort*)(w + 19*MB);     // 2 MB -> peak 21 MB

  // prep
  k_cvtZ<<<4096, 256, 0, stream>>>(Z, AZ);
  k_transpose<<<dim3(8,  8), 256, 0, stream>>>(Wo,  BoR,  256,  256, 512,   0);
  k_transpose<<<dim3(8,  8), 256, 0, stream>>>(Wr,  BoR,  256,  256, 512, 256);
  k_transpose<<<dim3(8, 32), 256, 0, stream>>>(f1w, f1T,  256, 1024, 256,   0);
  k_transpose<<<dim3(32,16), 256, 0, stream>>>(f2w, f2T, 1024,  512, 1024,  0);
  k_transpose<<<dim3(16, 8), 256, 0, stream>>>(f3w, f3T,  512,  256, 512,   0);
  k_biasor<<<1, 256, 0, stream>>>(bo, br, biasOR);

  // QKV + V transpose
  k_qkv<<<256, 256, 0, stream>>>(Zg, Zc, Wq, bq, Wk, bk, Wv, bv, qb, kbuf, vb);
  k_vtrans<<<dim3(64, 4), 256, 0, stream>>>(vb, vtb);

  // fused attention (single pass): attn (f32, NT) + AZ (bf16)
  k_attn3<<<1024, 1024, 0, stream>>>(qb, kbuf, vtb, adj, attnF, AZ);

  // [attended|Z] @ [Wo;Wr]^T + (bo+br) -> LN1 -> yf (f32) + yb (bf16)   [fused]
  k_gemm_ln<<<128, 256, 0, stream>>>(AZ, BoR, biasOR, nullptr,
                                     ln1g, ln1b, yf, yb, 512);

  // FFN
  k_gemm<<<dim3(64,16), 256, 0, stream>>>(yb, f1T, f1b, nullptr, nullptr, h1,
                                          4096, 1024, 256, 1);
  k_gemm<<<dim3(64, 8), 256, 0, stream>>>(h1, f2T, f2b, nullptr, nullptr, h2,
                                          4096, 512, 1024, 1);
  // h2 @ f3T^T + f3b + yf -> LN2 -> outF (f32)   [fused]
  k_gemm_ln<<<128, 256, 0, stream>>>(h2, f3T, f3b, yf,
                                     ln2g, ln2b, outF, nullptr, 512);
}

// Round 17
// 283.436 us; speedup vs baseline: 1.4105x; 1.0674x over previous
//
#include <hip/hip_runtime.h>
#include <cmath>

typedef __attribute__((ext_vector_type(8))) short bf16x8;
typedef __attribute__((ext_vector_type(4))) float f32x4;

#define MFMA16(A,B,C) __builtin_amdgcn_mfma_f32_16x16x32_bf16(A,B,C,0,0,0)

__device__ __forceinline__ ushort f2bf(float x){
  union { float f; unsigned u; } v; v.f = x;
  unsigned r = (v.u + 0x7fffu + ((v.u >> 16) & 1u)) >> 16;
  return (ushort)r;
}
__device__ __forceinline__ float bf2f(ushort h){
  union { unsigned u; float f; } v; v.u = ((unsigned)h) << 16;
  return v.f;
}

// ---------------- prep ----------------

__global__ __launch_bounds__(256) void k_cvtZ(const float* Z, ushort* AZ){
  int r = blockIdx.x, c = threadIdx.x;
  AZ[(size_t)r*512 + 256 + c] = f2bf(Z[(size_t)r*256 + c]);
}

__global__ __launch_bounds__(256) void k_transpose(const float* in, ushort* out,
                                                   int K, int N, int RS, int CO){
  __shared__ float t[32][33];
  int kb = blockIdx.x*32, nb = blockIdx.y*32;
  int tx = threadIdx.x & 31, ty = threadIdx.x >> 5;
  for (int i = ty; i < 32; i += 8){
    int k = kb + i, n = nb + tx;
    t[i][tx] = (k < K && n < N) ? in[(size_t)k*N + n] : 0.f;
  }
  __syncthreads();
  for (int i = ty; i < 32; i += 8){
    int n = nb + i, k = kb + tx;
    if (n < N && k < K) out[(size_t)n*RS + CO + k] = f2bf(t[tx][i]);
  }
}

__global__ void k_biasor(const float* bo, const float* br, float* out){
  int j = threadIdx.x;
  out[j] = bo[j] + br[j];
}

// ---------------- QKV: 16 rows/block, thread j = out col ----------------
__global__ __launch_bounds__(256) void k_qkv(
    const float* Zg, const float* Zc,
    const float* Wq, const float* bq, const float* Wk, const float* bk,
    const float* Wv, const float* bv,
    ushort* qb, ushort* kbuf, ushort* vb){
  __shared__ float zcp[16][128], zgp[16][128];
  int r0 = blockIdx.x * 16;
  int t = threadIdx.x;
  for (int i = t; i < 2048; i += 256){
    int row = i >> 7, c = i & 127;
    float vc, vg;
    if (c < 64){
      vc = Zc[(size_t)(r0+row)*64 + c];
      vg = Zg[(size_t)(r0+row)*64 + c];
    } else {
      int ii = (c - 64) >> 1;
      float div = __expf(-0.28782313662425572f * (float)ii);  // 10000^(-ii/32)
      float arg = (float)(r0 + row) * div;
      float pe = ((c - 64) & 1) ? cosf(arg) : sinf(arg);
      vc = pe; vg = pe;
    }
    zcp[row][c] = vc; zgp[row][c] = vg;
  }
  __syncthreads();
  float aq[16], ak[16], av[16];
  #pragma unroll
  for (int r = 0; r < 16; r++){ aq[r]=0.f; ak[r]=0.f; av[r]=0.f; }
  int j = t;
  #pragma unroll 4
  for (int k = 0; k < 128; k++){
    float wq = Wq[(size_t)k*256 + j];
    float wk = Wk[(size_t)k*256 + j];
    float wv = Wv[(size_t)k*256 + j];
    #pragma unroll
    for (int r = 0; r < 16; r++){
      float xc = zcp[r][k], xg = zgp[r][k];
      aq[r] = fmaf(xc, wq, aq[r]);
      ak[r] = fmaf(xg, wk, ak[r]);
      av[r] = fmaf(xg, wv, av[r]);
    }
  }
  int h = j >> 6, d = j & 63;
  float bqv = bq[j], bkv = bk[j], bvv = bv[j];
  #pragma unroll
  for (int r = 0; r < 16; r++){
    size_t base = ((size_t)h*4096 + (r0 + r))*64 + d;
    qb[base]   = f2bf((aq[r] + bqv) * 0.125f);  // fold 1/sqrt(64)
    kbuf[base] = f2bf(ak[r] + bkv);
    vb[base]   = f2bf(av[r] + bvv);
  }
}

// vb [h][4096][64] -> vtb [h][64][4096]
__global__ __launch_bounds__(256) void k_vtrans(const ushort* vb, ushort* vtb){
  __shared__ ushort t[64][65];
  int h = blockIdx.y, n0 = blockIdx.x * 64;
  int tx = threadIdx.x & 63, ty = threadIdx.x >> 6;
  for (int i = ty; i < 64; i += 4)
    t[i][tx] = vb[((size_t)h*4096 + n0 + i)*64 + tx];
  __syncthreads();
  for (int i = ty; i < 64; i += 4)
    vtb[((size_t)h*64 + i)*4096 + n0 + tx] = t[tx][i];
}

// ---------------- fused attention: SINGLE PASS, full P tile in LDS ----------------
// R14 structure + deeper phase-1 ILP (unroll 4, hoisted next-iter pointers).
__global__ __launch_bounds__(1024, 4) void k_attn3(
    const ushort* qb, const ushort* kbuf, const ushort* vtb,
    const float* adj, float* attn_out, ushort* az){
  __shared__ __align__(16) char smem[16*4096*2];   // 128 KB: pbf / pvp alias
  __shared__ float red[16][16];
  __shared__ float rsl[16];
  ushort* pbf = (ushort*)smem;                     // [16][4096], XOR-swizzled
  float (*pvp)[16][66] = (float(*)[16][66])smem;   // [16waves][16rows][64d+pad]

  int bid = blockIdx.x;
  int xcd = bid & 7, slot = bid >> 3;
  int nb = xcd*32 + (slot >> 2);
  int h  = slot & 3;
  int n0 = nb * 16;

  int t = threadIdx.x;
  int wave = t >> 6, lane = t & 63, lr = lane & 15, lg = lane >> 4;

  const ushort* Qh = qb   + ((size_t)h*4096 + n0)*64;
  const ushort* Kh = kbuf + (size_t)h*4096*64;
  const ushort* Vt = vtb  + (size_t)h*64*4096;
  float* aout = attn_out + (size_t)h*4096*4096 + (size_t)n0*4096;

  bf16x8 afr0 = *(const bf16x8*)(Qh + (size_t)lr*64 +  0 + lg*8);
  bf16x8 afr1 = *(const bf16x8*)(Qh + (size_t)lr*64 + 32 + lg*8);

  // ---- phase 1: QK^T + exp + rowsum + P->LDS (no barriers, deep ILP) ----
  const ushort* kp0 = Kh  + (size_t)(wave*16 + lr)*64 + lg*8;        // +256*64/iter
  const float*  ap0 = adj + (size_t)(n0 + lg*4)*4096 + wave*16 + lr; // +256/iter
  float rsum[4] = {0.f, 0.f, 0.f, 0.f};
  #pragma unroll 4
  for (int ct = 0; ct < 16; ct++){
    const ushort* kp = kp0 + (size_t)ct*16384;     // 256 rows * 64
    const float*  ap = ap0 + ct*256;
    bf16x8 b0 = *(const bf16x8*)(kp);
    bf16x8 b1 = *(const bf16x8*)(kp + 32);
    float a0 = ap[0], a1 = ap[4096], a2 = ap[8192], a3 = ap[12288];
    f32x4 acc = {0.f, 0.f, 0.f, 0.f};
    acc = MFMA16(afr0, b0, acc);
    acc = MFMA16(afr1, b1, acc);
    float p0 = a0 * __expf(acc[0]);
    float p1 = a1 * __expf(acc[1]);
    float p2 = a2 * __expf(acc[2]);
    float p3 = a3 * __expf(acc[3]);
    rsum[0] += p0; rsum[1] += p1; rsum[2] += p2; rsum[3] += p3;
    int col = ct*256 + wave*16 + lr;
    float p4[4] = {p0, p1, p2, p3};
    #pragma unroll
    for (int r = 0; r < 4; r++){
      int row = lg*4 + r;
      pbf[row*4096 + (col ^ ((row & 7) << 3))] = f2bf(p4[r]);
    }
  }
  #pragma unroll
  for (int m = 1; m <= 8; m <<= 1){
    #pragma unroll
    for (int r = 0; r < 4; r++) rsum[r] += __shfl_xor(rsum[r], m, 64);
  }
  if (lr == 0){
    #pragma unroll
    for (int r = 0; r < 4; r++) red[wave][lg*4 + r] = rsum[r];
  }
  __syncthreads();
  if (t < 16){
    float s = 0.f;
    #pragma unroll
    for (int w2 = 0; w2 < 16; w2++) s += red[w2][t];
    rsl[t] = 1.f / s;
  }
  __syncthreads();

  // ---- phase 3: normalized attn stores (wave sweeps row `wave`) ----
  {
    int row = wave;
    float iv = rsl[row];
    int swz = (row & 7) << 3;
    #pragma unroll 2
    for (int q = 0; q < 16; q++){
      int c = q*256 + lane*4;
      const ushort* src = &pbf[row*4096 + (c ^ swz)];
      ushort s4[4];
      *(uint2*)s4 = *(const uint2*)src;
      f32x4 ov = {bf2f(s4[0])*iv, bf2f(s4[1])*iv, bf2f(s4[2])*iv, bf2f(s4[3])*iv};
      __builtin_nontemporal_store(ov, (f32x4*)(aout + (size_t)row*4096 + c));
    }
  }

  // ---- phase 4: PV from LDS (wave owns k-slice [wave*256, wave*256+256)) ----
  f32x4 pacc[4];
  #pragma unroll
  for (int d = 0; d < 4; d++) pacc[d] = (f32x4){0.f,0.f,0.f,0.f};
  #pragma unroll
  for (int ks = 0; ks < 8; ks++){
    int kb2 = wave*256 + ks*32;
    bf16x8 pa = *(const bf16x8*)&pbf[lr*4096 + ((kb2 + lg*8) ^ ((lr & 7) << 3))];
    #pragma unroll
    for (int df = 0; df < 4; df++){
      bf16x8 v8 = *(const bf16x8*)(Vt + (size_t)(df*16 + lr)*4096 + kb2 + lg*8);
      pacc[df] = MFMA16(pa, v8, pacc[df]);
    }
  }

  // ---- phase 5: cross-wave PV reduce (pvp aliases pbf) -> AZ ----
  __syncthreads();
  #pragma unroll
  for (int df = 0; df < 4; df++)
    #pragma unroll
    for (int r = 0; r < 4; r++)
      pvp[wave][lg*4 + r][df*16 + lr] = pacc[df][r];
  __syncthreads();
  {
    int row = t >> 6;
    int d   = t & 63;
    float s = 0.f;
    #pragma unroll
    for (int w2 = 0; w2 < 16; w2++) s += pvp[w2][row][d];
    s *= rsl[row];
    az[(size_t)(n0 + row)*512 + h*64 + d] = f2bf(s);
  }
}

// ---------------- generic GEMM: C = act(A @ Bt^T + bias [+ res]) ----------------
__global__ __launch_bounds__(256) void k_gemm(
    const ushort* A, const ushort* Bt, const float* bias,
    const float* res, float* outf, ushort* outb,
    int M, int N, int K, int mode){
  __shared__ __align__(16) ushort la[64][40];
  __shared__ __align__(16) ushort lb[64][40];
  int mb = blockIdx.x * 64, nb = blockIdx.y * 64;
  int t = threadIdx.x;
  int wave = t >> 6, lane = t & 63, lr = lane & 15, lg = lane >> 4;
  int wm = (wave >> 1) * 32, wn = (wave & 1) * 32;
  f32x4 acc[2][2];
  #pragma unroll
  for (int i = 0; i < 2; i++)
    #pragma unroll
    for (int j = 0; j < 2; j++) acc[i][j] = (f32x4){0.f,0.f,0.f,0.f};

  int srow = t >> 2, scol = (t & 3) * 8;
  for (int k0 = 0; k0 < K; k0 += 32){
    *(bf16x8*)&la[srow][scol] = *(const bf16x8*)(A  + (size_t)(mb+srow)*K + k0 + scol);
    *(bf16x8*)&lb[srow][scol] = *(const bf16x8*)(Bt + (size_t)(nb+srow)*K + k0 + scol);
    __syncthreads();
    #pragma unroll
    for (int i = 0; i < 2; i++){
      bf16x8 af = *(const bf16x8*)&la[wm + i*16 + lr][lg*8];
      #pragma unroll
      for (int j = 0; j < 2; j++){
        bf16x8 bfg = *(const bf16x8*)&lb[wn + j*16 + lr][lg*8];
        acc[i][j] = MFMA16(af, bfg, acc[i][j]);
      }
    }
    __syncthreads();
  }

  #pragma unroll
  for (int i = 0; i < 2; i++)
    #pragma unroll
    for (int j = 0; j < 2; j++){
      int col = nb + wn + j*16 + lr;
      float bv = bias[col];
      #pragma unroll
      for (int r = 0; r < 4; r++){
        int row = mb + wm + i*16 + lg*4 + r;
        float v = acc[i][j][r] + bv;
        if (mode == 0){
          if (res) v += res[(size_t)row*N + col];
          outf[(size_t)row*N + col] = v;
        } else {
          float gl = 0.5f * v * (1.f + erff(v * 0.70710678118f));
          outb[(size_t)row*N + col] = f2bf(gl);
        }
      }
    }
}

// ---------------- LayerNorm over 256 cols, wave per row ----------------
__global__ __launch_bounds__(256) void k_ln(const float* X, const float* g, const float* b,
                                            float* outf, ushort* outb){
  int row = blockIdx.x * 4 + (threadIdx.x >> 6);
  int lane = threadIdx.x & 63;
  const float* xr = X + (size_t)row*256;
  f32x4 v = *(const f32x4*)(xr + lane*4);
  float s = v[0] + v[1] + v[2] + v[3];
  #pragma unroll
  for (int m = 32; m >= 1; m >>= 1) s += __shfl_xor(s, m, 64);
  float mean = s * (1.f/256.f);
  float d0[4]; float sq = 0.f;
  #pragma unroll
  for (int e = 0; e < 4; e++){ d0[e] = v[e] - mean; sq += d0[e]*d0[e]; }
  #pragma unroll
  for (int m = 32; m >= 1; m >>= 1) sq += __shfl_xor(sq, m, 64);
  float rstd = rsqrtf(sq * (1.f/256.f) + 1e-5f);
  float o[4];
  #pragma unroll
  for (int e = 0; e < 4; e++)
    o[e] = d0[e]*rstd*g[lane*4 + e] + b[lane*4 + e];
  if (outf){
    f32x4 ov = {o[0], o[1], o[2], o[3]};
    *(f32x4*)(outf + (size_t)row*256 + lane*4) = ov;
  }
  if (outb){
    union { ushort u[4]; uint2 q; } pk;
    #pragma unroll
    for (int e = 0; e < 4; e++) pk.u[e] = f2bf(o[e]);
    *(uint2*)(outb + (size_t)row*256 + lane*4) = pk.q;
  }
}

// ---------------- launch ----------------
extern "C" void kernel_launch(void* const* d_in, const int* in_sizes, int n_in,
                              void* d_out, int out_size, void* d_ws, size_t ws_size,
                              hipStream_t stream){
  const float* Z    = (const float*)d_in[0];
  const float* Zg   = (const float*)d_in[1];
  const float* Zc   = (const float*)d_in[2];
  const float* adj  = (const float*)d_in[3];
  const float* Wq   = (const float*)d_in[4];
  const float* bq   = (const float*)d_in[5];
  const float* Wk   = (const float*)d_in[6];
  const float* bk   = (const float*)d_in[7];
  const float* Wv   = (const float*)d_in[8];
  const float* bv   = (const float*)d_in[9];
  const float* Wo   = (const float*)d_in[10];
  const float* bo   = (const float*)d_in[11];
  const float* Wr   = (const float*)d_in[12];
  const float* br   = (const float*)d_in[13];
  const float* ln1g = (const float*)d_in[14];
  const float* ln1b = (const float*)d_in[15];
  const float* ln2g = (const float*)d_in[16];
  const float* ln2b = (const float*)d_in[17];
  const float* f1w  = (const float*)d_in[18];
  const float* f1b  = (const float*)d_in[19];
  const float* f2w  = (const float*)d_in[20];
  const float* f2b  = (const float*)d_in[21];
  const float* f3w  = (const float*)d_in[22];
  const float* f3b  = (const float*)d_in[23];

  // OUTPUTS: f32 out [4096*256] then f32 attn [4*4096*4096]
  float* outF  = (float*)d_out;
  float* attnF = outF + (size_t)4096*256;

  const size_t MB = 1048576;
  char* w = (char*)d_ws;
  ushort* qb    = (ushort*)(w + 0*MB);      // 2 MB, dead after k_attn3
  ushort* kbuf  = (ushort*)(w + 2*MB);      // 2 MB, dead after k_attn3
  ushort* vtb   = (ushort*)(w + 4*MB);      // 2 MB, dead after k_attn3
  ushort* vb    = (ushort*)(w + 6*MB);      // 2 MB, dead after k_vtrans
  ushort* h1    = (ushort*)(w + 0*MB);      // 8 MB, written after k_attn3
  ushort* AZ    = (ushort*)(w + 8*MB);      // 4 MB, dead after gemm1
  ushort* h2    = (ushort*)(w + 8*MB);      // 4 MB, written after gemm1
  ushort* BoR   = (ushort*)(w + 12*MB);                 // 256 KB [256][512]
  float*  biasOR= (float*)(w + 12*MB + 262144);         // 1 KB
  ushort* f1T   = (ushort*)(w + 13*MB);     // 512 KB [1024][256]
  ushort* f2T   = (ushort*)(w + 13*MB + 524288);  // 1 MB [512][1024]
  ushort* f3T   = (ushort*)(w + 14*MB + 524288);  // 256 KB [256][512]
  float*  X1    = (float*)(w + 15*MB);      // 4 MB
  float*  yf    = (float*)(w + 19*MB);      // 4 MB
  ushort* yb    = (ushort*)(w + 23*MB);     // 2 MB -> peak 25 MB

  // prep
  k_cvtZ<<<4096, 256, 0, stream>>>(Z, AZ);
  k_transpose<<<dim3(8,  8), 256, 0, stream>>>(Wo,  BoR,  256,  256, 512,   0);
  k_transpose<<<dim3(8,  8), 256, 0, stream>>>(Wr,  BoR,  256,  256, 512, 256);
  k_transpose<<<dim3(8, 32), 256, 0, stream>>>(f1w, f1T,  256, 1024, 256,   0);
  k_transpose<<<dim3(32,16), 256, 0, stream>>>(f2w, f2T, 1024,  512, 1024,  0);
  k_transpose<<<dim3(16, 8), 256, 0, stream>>>(f3w, f3T,  512,  256, 512,   0);
  k_biasor<<<1, 256, 0, stream>>>(bo, br, biasOR);

  // QKV + V transpose
  k_qkv<<<256, 256, 0, stream>>>(Zg, Zc, Wq, bq, Wk, bk, Wv, bv, qb, kbuf, vb);
  k_vtrans<<<dim3(64, 4), 256, 0, stream>>>(vb, vtb);

  // fused attention (single pass): normalized attn (f32, NT) + attended AZ (bf16)
  k_attn3<<<1024, 1024, 0, stream>>>(qb, kbuf, vtb, adj, attnF, AZ);

  // X1 = [attended|Z] @ [Wo;Wr]^T + (bo+br)
  k_gemm<<<dim3(64, 4), 256, 0, stream>>>(AZ, BoR, biasOR, nullptr, X1, nullptr,
                                          4096, 256, 512, 0);
  k_ln<<<1024, 256, 0, stream>>>(X1, ln1g, ln1b, yf, yb);

  // FFN
  k_gemm<<<dim3(64,16), 256, 0, stream>>>(yb, f1T, f1b, nullptr, nullptr, h1,
                                          4096, 1024, 256, 1);
  k_gemm<<<dim3(64, 8), 256, 0, stream>>>(h1, f2T, f2b, nullptr, nullptr, h2,
                                          4096, 512, 1024, 1);
  k_gemm<<<dim3(64, 4), 256, 0, stream>>>(h2, f3T, f3b, yf, X1, nullptr,
                                          4096, 256, 512, 0);
  k_ln<<<1024, 256, 0, stream>>>(X1, ln2g, ln2b, outF, nullptr);
}

// Round 18
// 275.024 us; speedup vs baseline: 1.4536x; 1.0306x over previous
//
#include <hip/hip_runtime.h>
#include <cmath>

typedef __attribute__((ext_vector_type(8))) short bf16x8;
typedef __attribute__((ext_vector_type(4))) float f32x4;

#define MFMA16(A,B,C) __builtin_amdgcn_mfma_f32_16x16x32_bf16(A,B,C,0,0,0)

__device__ __forceinline__ ushort f2bf(float x){
  union { float f; unsigned u; } v; v.f = x;
  unsigned r = (v.u + 0x7fffu + ((v.u >> 16) & 1u)) >> 16;
  return (ushort)r;
}
__device__ __forceinline__ float bf2f(ushort h){
  union { unsigned u; float f; } v; v.u = ((unsigned)h) << 16;
  return v.f;
}

// ---------------- prep ----------------

__global__ __launch_bounds__(256) void k_cvtZ(const float* Z, ushort* AZ){
  int r = blockIdx.x, c = threadIdx.x;
  AZ[(size_t)r*512 + 256 + c] = f2bf(Z[(size_t)r*256 + c]);
}

__global__ __launch_bounds__(256) void k_transpose(const float* in, ushort* out,
                                                   int K, int N, int RS, int CO){
  __shared__ float t[32][33];
  int kb = blockIdx.x*32, nb = blockIdx.y*32;
  int tx = threadIdx.x & 31, ty = threadIdx.x >> 5;
  for (int i = ty; i < 32; i += 8){
    int k = kb + i, n = nb + tx;
    t[i][tx] = (k < K && n < N) ? in[(size_t)k*N + n] : 0.f;
  }
  __syncthreads();
  for (int i = ty; i < 32; i += 8){
    int n = nb + i, k = kb + tx;
    if (n < N && k < K) out[(size_t)n*RS + CO + k] = f2bf(t[tx][i]);
  }
}

__global__ void k_biasor(const float* bo, const float* br, float* out){
  int j = threadIdx.x;
  out[j] = bo[j] + br[j];
}

// ---------------- QKV: 16 rows/block, thread j = out col ----------------
__global__ __launch_bounds__(256) void k_qkv(
    const float* Zg, const float* Zc,
    const float* Wq, const float* bq, const float* Wk, const float* bk,
    const float* Wv, const float* bv,
    ushort* qb, ushort* kbuf, ushort* vb){
  __shared__ float zcp[16][128], zgp[16][128];
  int r0 = blockIdx.x * 16;
  int t = threadIdx.x;
  for (int i = t; i < 2048; i += 256){
    int row = i >> 7, c = i & 127;
    float vc, vg;
    if (c < 64){
      vc = Zc[(size_t)(r0+row)*64 + c];
      vg = Zg[(size_t)(r0+row)*64 + c];
    } else {
      int ii = (c - 64) >> 1;
      float div = __expf(-0.28782313662425572f * (float)ii);  // 10000^(-ii/32)
      float arg = (float)(r0 + row) * div;
      float pe = ((c - 64) & 1) ? cosf(arg) : sinf(arg);
      vc = pe; vg = pe;
    }
    zcp[row][c] = vc; zgp[row][c] = vg;
  }
  __syncthreads();
  float aq[16], ak[16], av[16];
  #pragma unroll
  for (int r = 0; r < 16; r++){ aq[r]=0.f; ak[r]=0.f; av[r]=0.f; }
  int j = t;
  #pragma unroll 4
  for (int k = 0; k < 128; k++){
    float wq = Wq[(size_t)k*256 + j];
    float wk = Wk[(size_t)k*256 + j];
    float wv = Wv[(size_t)k*256 + j];
    #pragma unroll
    for (int r = 0; r < 16; r++){
      float xc = zcp[r][k], xg = zgp[r][k];
      aq[r] = fmaf(xc, wq, aq[r]);
      ak[r] = fmaf(xg, wk, ak[r]);
      av[r] = fmaf(xg, wv, av[r]);
    }
  }
  int h = j >> 6, d = j & 63;
  float bqv = bq[j], bkv = bk[j], bvv = bv[j];
  #pragma unroll
  for (int r = 0; r < 16; r++){
    size_t base = ((size_t)h*4096 + (r0 + r))*64 + d;
    qb[base]   = f2bf((aq[r] + bqv) * 0.125f);  // fold 1/sqrt(64)
    kbuf[base] = f2bf(ak[r] + bkv);
    vb[base]   = f2bf(av[r] + bvv);
  }
}

// vb [h][4096][64] -> vtb [h][64][4096]
__global__ __launch_bounds__(256) void k_vtrans(const ushort* vb, ushort* vtb){
  __shared__ ushort t[64][65];
  int h = blockIdx.y, n0 = blockIdx.x * 64;
  int tx = threadIdx.x & 63, ty = threadIdx.x >> 6;
  for (int i = ty; i < 64; i += 4)
    t[i][tx] = vb[((size_t)h*4096 + n0 + i)*64 + tx];
  __syncthreads();
  for (int i = ty; i < 64; i += 4)
    vtb[((size_t)h*64 + i)*4096 + n0 + tx] = t[tx][i];
}

// ---------------- fused attention: PERSISTENT single-pass ----------------
// grid = 256 (1 block/CU); block b owns 16-row strip b and loops over the 4
// heads. Strip i's store drain overlaps strip i+1's phase-1 (no endpgm
// between); adj rows read once per block, reused 4x (L2-hot).
__global__ __launch_bounds__(1024, 4) void k_attn3(
    const ushort* qb, const ushort* kbuf, const ushort* vtb,
    const float* adj, float* attn_out, ushort* az){
  __shared__ __align__(16) char smem[16*4096*2];   // 128 KB: pbf / pvp alias
  __shared__ float red[16][16];
  __shared__ float rsl[16];
  ushort* pbf = (ushort*)smem;                     // [16][4096], XOR-swizzled
  float (*pvp)[16][66] = (float(*)[16][66])smem;   // [16waves][16rows][64d+pad]

  int nb = blockIdx.x;                             // strip 0..255
  int n0 = nb * 16;
  int t = threadIdx.x;
  int wave = t >> 6, lane = t & 63, lr = lane & 15, lg = lane >> 4;

  for (int h = 0; h < 4; h++){
    const ushort* Qh = qb   + ((size_t)h*4096 + n0)*64;
    const ushort* Kh = kbuf + (size_t)h*4096*64;
    const ushort* Vt = vtb  + (size_t)h*64*4096;
    float* aout = attn_out + (size_t)h*4096*4096 + (size_t)n0*4096;

    bf16x8 afr0 = *(const bf16x8*)(Qh + (size_t)lr*64 +  0 + lg*8);
    bf16x8 afr1 = *(const bf16x8*)(Qh + (size_t)lr*64 + 32 + lg*8);

    // ---- phase 1: QK^T + exp + rowsum + P->LDS (no barriers) ----
    const ushort* kp0 = Kh  + (size_t)(wave*16 + lr)*64 + lg*8;
    const float*  ap0 = adj + (size_t)(n0 + lg*4)*4096 + wave*16 + lr;
    float rsum[4] = {0.f, 0.f, 0.f, 0.f};
    #pragma unroll 2
    for (int ct = 0; ct < 16; ct++){
      const ushort* kp = kp0 + (size_t)ct*16384;   // 256 rows * 64
      const float*  ap = ap0 + ct*256;
      bf16x8 b0 = *(const bf16x8*)(kp);
      bf16x8 b1 = *(const bf16x8*)(kp + 32);
      float a0 = ap[0], a1 = ap[4096], a2 = ap[8192], a3 = ap[12288];
      f32x4 acc = {0.f, 0.f, 0.f, 0.f};
      acc = MFMA16(afr0, b0, acc);
      acc = MFMA16(afr1, b1, acc);
      float p0 = a0 * __expf(acc[0]);
      float p1 = a1 * __expf(acc[1]);
      float p2 = a2 * __expf(acc[2]);
      float p3 = a3 * __expf(acc[3]);
      rsum[0] += p0; rsum[1] += p1; rsum[2] += p2; rsum[3] += p3;
      int col = ct*256 + wave*16 + lr;
      float p4[4] = {p0, p1, p2, p3};
      #pragma unroll
      for (int r = 0; r < 4; r++){
        int row = lg*4 + r;
        pbf[row*4096 + (col ^ ((row & 7) << 3))] = f2bf(p4[r]);
      }
    }
    #pragma unroll
    for (int m = 1; m <= 8; m <<= 1){
      #pragma unroll
      for (int r = 0; r < 4; r++) rsum[r] += __shfl_xor(rsum[r], m, 64);
    }
    if (lr == 0){
      #pragma unroll
      for (int r = 0; r < 4; r++) red[wave][lg*4 + r] = rsum[r];
    }
    __syncthreads();
    if (t < 16){
      float s = 0.f;
      #pragma unroll
      for (int w2 = 0; w2 < 16; w2++) s += red[w2][t];
      rsl[t] = 1.f / s;
    }
    __syncthreads();

    // ---- phase 3: normalized attn stores (wave sweeps row `wave`) ----
    {
      int row = wave;
      float iv = rsl[row];
      int swz = (row & 7) << 3;
      #pragma unroll 2
      for (int q = 0; q < 16; q++){
        int c = q*256 + lane*4;
        const ushort* src = &pbf[row*4096 + (c ^ swz)];
        ushort s4[4];
        *(uint2*)s4 = *(const uint2*)src;
        f32x4 ov = {bf2f(s4[0])*iv, bf2f(s4[1])*iv, bf2f(s4[2])*iv, bf2f(s4[3])*iv};
        __builtin_nontemporal_store(ov, (f32x4*)(aout + (size_t)row*4096 + c));
      }
    }

    // ---- phase 4: PV from LDS (wave owns k-slice [wave*256, +256)) ----
    f32x4 pacc[4];
    #pragma unroll
    for (int d = 0; d < 4; d++) pacc[d] = (f32x4){0.f,0.f,0.f,0.f};
    #pragma unroll
    for (int ks = 0; ks < 8; ks++){
      int kb2 = wave*256 + ks*32;
      bf16x8 pa = *(const bf16x8*)&pbf[lr*4096 + ((kb2 + lg*8) ^ ((lr & 7) << 3))];
      #pragma unroll
      for (int df = 0; df < 4; df++){
        bf16x8 v8 = *(const bf16x8*)(Vt + (size_t)(df*16 + lr)*4096 + kb2 + lg*8);
        pacc[df] = MFMA16(pa, v8, pacc[df]);
      }
    }

    // ---- phase 5: cross-wave PV reduce (pvp aliases pbf) -> AZ ----
    __syncthreads();                  // all pbf reads (stores + PV) done
    #pragma unroll
    for (int df = 0; df < 4; df++)
      #pragma unroll
      for (int r = 0; r < 4; r++)
        pvp[wave][lg*4 + r][df*16 + lr] = pacc[df][r];
    __syncthreads();
    {
      int row = t >> 6;
      int d   = t & 63;
      float s = 0.f;
      #pragma unroll
      for (int w2 = 0; w2 < 16; w2++) s += pvp[w2][row][d];
      s *= rsl[row];
      az[(size_t)(n0 + row)*512 + h*64 + d] = f2bf(s);
    }
    __syncthreads();                  // pvp reads done before next h's phase-1
  }
}

// ---------------- generic GEMM: C = act(A @ Bt^T + bias [+ res]) ----------------
__global__ __launch_bounds__(256) void k_gemm(
    const ushort* A, const ushort* Bt, const float* bias,
    const float* res, float* outf, ushort* outb,
    int M, int N, int K, int mode){
  __shared__ __align__(16) ushort la[64][40];
  __shared__ __align__(16) ushort lb[64][40];
  int mb = blockIdx.x * 64, nb = blockIdx.y * 64;
  int t = threadIdx.x;
  int wave = t >> 6, lane = t & 63, lr = lane & 15, lg = lane >> 4;
  int wm = (wave >> 1) * 32, wn = (wave & 1) * 32;
  f32x4 acc[2][2];
  #pragma unroll
  for (int i = 0; i < 2; i++)
    #pragma unroll
    for (int j = 0; j < 2; j++) acc[i][j] = (f32x4){0.f,0.f,0.f,0.f};

  int srow = t >> 2, scol = (t & 3) * 8;
  for (int k0 = 0; k0 < K; k0 += 32){
    *(bf16x8*)&la[srow][scol] = *(const bf16x8*)(A  + (size_t)(mb+srow)*K + k0 + scol);
    *(bf16x8*)&lb[srow][scol] = *(const bf16x8*)(Bt + (size_t)(nb+srow)*K + k0 + scol);
    __syncthreads();
    #pragma unroll
    for (int i = 0; i < 2; i++){
      bf16x8 af = *(const bf16x8*)&la[wm + i*16 + lr][lg*8];
      #pragma unroll
      for (int j = 0; j < 2; j++){
        bf16x8 bfg = *(const bf16x8*)&lb[wn + j*16 + lr][lg*8];
        acc[i][j] = MFMA16(af, bfg, acc[i][j]);
      }
    }
    __syncthreads();
  }

  #pragma unroll
  for (int i = 0; i < 2; i++)
    #pragma unroll
    for (int j = 0; j < 2; j++){
      int col = nb + wn + j*16 + lr;
      float bv = bias[col];
      #pragma unroll
      for (int r = 0; r < 4; r++){
        int row = mb + wm + i*16 + lg*4 + r;
        float v = acc[i][j][r] + bv;
        if (mode == 0){
          if (res) v += res[(size_t)row*N + col];
          outf[(size_t)row*N + col] = v;
        } else {
          float gl = 0.5f * v * (1.f + erff(v * 0.70710678118f));
          outb[(size_t)row*N + col] = f2bf(gl);
        }
      }
    }
}

// ---------------- LayerNorm over 256 cols, wave per row ----------------
__global__ __launch_bounds__(256) void k_ln(const float* X, const float* g, const float* b,
                                            float* outf, ushort* outb){
  int row = blockIdx.x * 4 + (threadIdx.x >> 6);
  int lane = threadIdx.x & 63;
  const float* xr = X + (size_t)row*256;
  f32x4 v = *(const f32x4*)(xr + lane*4);
  float s = v[0] + v[1] + v[2] + v[3];
  #pragma unroll
  for (int m = 32; m >= 1; m >>= 1) s += __shfl_xor(s, m, 64);
  float mean = s * (1.f/256.f);
  float d0[4]; float sq = 0.f;
  #pragma unroll
  for (int e = 0; e < 4; e++){ d0[e] = v[e] - mean; sq += d0[e]*d0[e]; }
  #pragma unroll
  for (int m = 32; m >= 1; m >>= 1) sq += __shfl_xor(sq, m, 64);
  float rstd = rsqrtf(sq * (1.f/256.f) + 1e-5f);
  float o[4];
  #pragma unroll
  for (int e = 0; e < 4; e++)
    o[e] = d0[e]*rstd*g[lane*4 + e] + b[lane*4 + e];
  if (outf){
    f32x4 ov = {o[0], o[1], o[2], o[3]};
    *(f32x4*)(outf + (size_t)row*256 + lane*4) = ov;
  }
  if (outb){
    union { ushort u[4]; uint2 q; } pk;
    #pragma unroll
    for (int e = 0; e < 4; e++) pk.u[e] = f2bf(o[e]);
    *(uint2*)(outb + (size_t)row*256 + lane*4) = pk.q;
  }
}

// ---------------- launch ----------------
extern "C" void kernel_launch(void* const* d_in, const int* in_sizes, int n_in,
                              void* d_out, int out_size, void* d_ws, size_t ws_size,
                              hipStream_t stream){
  const float* Z    = (const float*)d_in[0];
  const float* Zg   = (const float*)d_in[1];
  const float* Zc   = (const float*)d_in[2];
  const float* adj  = (const float*)d_in[3];
  const float* Wq   = (const float*)d_in[4];
  const float* bq   = (const float*)d_in[5];
  const float* Wk   = (const float*)d_in[6];
  const float* bk   = (const float*)d_in[7];
  const float* Wv   = (const float*)d_in[8];
  const float* bv   = (const float*)d_in[9];
  const float* Wo   = (const float*)d_in[10];
  const float* bo   = (const float*)d_in[11];
  const float* Wr   = (const float*)d_in[12];
  const float* br   = (const float*)d_in[13];
  const float* ln1g = (const float*)d_in[14];
  const float* ln1b = (const float*)d_in[15];
  const float* ln2g = (const float*)d_in[16];
  const float* ln2b = (const float*)d_in[17];
  const float* f1w  = (const float*)d_in[18];
  const float* f1b  = (const float*)d_in[19];
  const float* f2w  = (const float*)d_in[20];
  const float* f2b  = (const float*)d_in[21];
  const float* f3w  = (const float*)d_in[22];
  const float* f3b  = (const float*)d_in[23];

  // OUTPUTS: f32 out [4096*256] then f32 attn [4*4096*4096]
  float* outF  = (float*)d_out;
  float* attnF = outF + (size_t)4096*256;

  const size_t MB = 1048576;
  char* w = (char*)d_ws;
  ushort* qb    = (ushort*)(w + 0*MB);      // 2 MB, dead after k_attn3
  ushort* kbuf  = (ushort*)(w + 2*MB);      // 2 MB, dead after k_attn3
  ushort* vtb   = (ushort*)(w + 4*MB);      // 2 MB, dead after k_attn3
  ushort* vb    = (ushort*)(w + 6*MB);      // 2 MB, dead after k_vtrans
  ushort* h1    = (ushort*)(w + 0*MB);      // 8 MB, written after k_attn3
  ushort* AZ    = (ushort*)(w + 8*MB);      // 4 MB, dead after gemm1
  ushort* h2    = (ushort*)(w + 8*MB);      // 4 MB, written after gemm1
  ushort* BoR   = (ushort*)(w + 12*MB);                 // 256 KB [256][512]
  float*  biasOR= (float*)(w + 12*MB + 262144);         // 1 KB
  ushort* f1T   = (ushort*)(w + 13*MB);     // 512 KB [1024][256]
  ushort* f2T   = (ushort*)(w + 13*MB + 524288);  // 1 MB [512][1024]
  ushort* f3T   = (ushort*)(w + 14*MB + 524288);  // 256 KB [256][512]
  float*  X1    = (float*)(w + 15*MB);      // 4 MB
  float*  yf    = (float*)(w + 19*MB);      // 4 MB
  ushort* yb    = (ushort*)(w + 23*MB);     // 2 MB -> peak 25 MB

  // prep
  k_cvtZ<<<4096, 256, 0, stream>>>(Z, AZ);
  k_transpose<<<dim3(8,  8), 256, 0, stream>>>(Wo,  BoR,  256,  256, 512,   0);
  k_transpose<<<dim3(8,  8), 256, 0, stream>>>(Wr,  BoR,  256,  256, 512, 256);
  k_transpose<<<dim3(8, 32), 256, 0, stream>>>(f1w, f1T,  256, 1024, 256,   0);
  k_transpose<<<dim3(32,16), 256, 0, stream>>>(f2w, f2T, 1024,  512, 1024,  0);
  k_transpose<<<dim3(16, 8), 256, 0, stream>>>(f3w, f3T,  512,  256, 512,   0);
  k_biasor<<<1, 256, 0, stream>>>(bo, br, biasOR);

  // QKV + V transpose
  k_qkv<<<256, 256, 0, stream>>>(Zg, Zc, Wq, bq, Wk, bk, Wv, bv, qb, kbuf, vb);
  k_vtrans<<<dim3(64, 4), 256, 0, stream>>>(vb, vtb);

  // fused attention (persistent): normalized attn (f32, NT) + attended AZ (bf16)
  k_attn3<<<256, 1024, 0, stream>>>(qb, kbuf, vtb, adj, attnF, AZ);

  // X1 = [attended|Z] @ [Wo;Wr]^T + (bo+br)
  k_gemm<<<dim3(64, 4), 256, 0, stream>>>(AZ, BoR, biasOR, nullptr, X1, nullptr,
                                          4096, 256, 512, 0);
  k_ln<<<1024, 256, 0, stream>>>(X1, ln1g, ln1b, yf, yb);

  // FFN
  k_gemm<<<dim3(64,16), 256, 0, stream>>>(yb, f1T, f1b, nullptr, nullptr, h1,
                                          4096, 1024, 256, 1);
  k_gemm<<<dim3(64, 8), 256, 0, stream>>>(h1, f2T, f2b, nullptr, nullptr, h2,
                                          4096, 512, 1024, 1);
  k_gemm<<<dim3(64, 4), 256, 0, stream>>>(h2, f3T, f3b, yf, X1, nullptr,
                                          4096, 256, 512, 0);
  k_ln<<<1024, 256, 0, stream>>>(X1, ln2g, ln2b, outF, nullptr);
}

// Round 19
// 270.038 us; speedup vs baseline: 1.4805x; 1.0185x over previous
//
#include <hip/hip_runtime.h>
#include <cmath>

typedef __attribute__((ext_vector_type(8))) short bf16x8;
typedef __attribute__((ext_vector_type(4))) float f32x4;

#define MFMA16(A,B,C) __builtin_amdgcn_mfma_f32_16x16x32_bf16(A,B,C,0,0,0)

__device__ __forceinline__ ushort f2bf(float x){
  union { float f; unsigned u; } v; v.f = x;
  unsigned r = (v.u + 0x7fffu + ((v.u >> 16) & 1u)) >> 16;
  return (ushort)r;
}
__device__ __forceinline__ float bf2f(ushort h){
  union { unsigned u; float f; } v; v.u = ((unsigned)h) << 16;
  return v.f;
}

// ---------------- prep ----------------

__global__ __launch_bounds__(256) void k_cvtZ(const float* Z, ushort* AZ){
  int r = blockIdx.x, c = threadIdx.x;
  AZ[(size_t)r*512 + 256 + c] = f2bf(Z[(size_t)r*256 + c]);
}

__global__ __launch_bounds__(256) void k_transpose(const float* in, ushort* out,
                                                   int K, int N, int RS, int CO){
  __shared__ float t[32][33];
  int kb = blockIdx.x*32, nb = blockIdx.y*32;
  int tx = threadIdx.x & 31, ty = threadIdx.x >> 5;
  for (int i = ty; i < 32; i += 8){
    int k = kb + i, n = nb + tx;
    t[i][tx] = (k < K && n < N) ? in[(size_t)k*N + n] : 0.f;
  }
  __syncthreads();
  for (int i = ty; i < 32; i += 8){
    int n = nb + i, k = kb + tx;
    if (n < N && k < K) out[(size_t)n*RS + CO + k] = f2bf(t[tx][i]);
  }
}

__global__ void k_biasor(const float* bo, const float* br, float* out){
  int j = threadIdx.x;
  out[j] = bo[j] + br[j];
}

// ---------------- QKV: 16 rows/block, thread j = out col ----------------
__global__ __launch_bounds__(256) void k_qkv(
    const float* Zg, const float* Zc,
    const float* Wq, const float* bq, const float* Wk, const float* bk,
    const float* Wv, const float* bv,
    ushort* qb, ushort* kbuf, ushort* vb){
  __shared__ float zcp[16][128], zgp[16][128];
  int r0 = blockIdx.x * 16;
  int t = threadIdx.x;
  for (int i = t; i < 2048; i += 256){
    int row = i >> 7, c = i & 127;
    float vc, vg;
    if (c < 64){
      vc = Zc[(size_t)(r0+row)*64 + c];
      vg = Zg[(size_t)(r0+row)*64 + c];
    } else {
      int ii = (c - 64) >> 1;
      float div = __expf(-0.28782313662425572f * (float)ii);  // 10000^(-ii/32)
      float arg = (float)(r0 + row) * div;
      float pe = ((c - 64) & 1) ? cosf(arg) : sinf(arg);
      vc = pe; vg = pe;
    }
    zcp[row][c] = vc; zgp[row][c] = vg;
  }
  __syncthreads();
  float aq[16], ak[16], av[16];
  #pragma unroll
  for (int r = 0; r < 16; r++){ aq[r]=0.f; ak[r]=0.f; av[r]=0.f; }
  int j = t;
  #pragma unroll 4
  for (int k = 0; k < 128; k++){
    float wq = Wq[(size_t)k*256 + j];
    float wk = Wk[(size_t)k*256 + j];
    float wv = Wv[(size_t)k*256 + j];
    #pragma unroll
    for (int r = 0; r < 16; r++){
      float xc = zcp[r][k], xg = zgp[r][k];
      aq[r] = fmaf(xc, wq, aq[r]);
      ak[r] = fmaf(xg, wk, ak[r]);
      av[r] = fmaf(xg, wv, av[r]);
    }
  }
  int h = j >> 6, d = j & 63;
  float bqv = bq[j], bkv = bk[j], bvv = bv[j];
  #pragma unroll
  for (int r = 0; r < 16; r++){
    size_t base = ((size_t)h*4096 + (r0 + r))*64 + d;
    qb[base]   = f2bf((aq[r] + bqv) * 0.125f);  // fold 1/sqrt(64)
    kbuf[base] = f2bf(ak[r] + bkv);
    vb[base]   = f2bf(av[r] + bvv);
  }
}

// vb [h][4096][64] -> vtb [h][64][4096]
__global__ __launch_bounds__(256) void k_vtrans(const ushort* vb, ushort* vtb){
  __shared__ ushort t[64][65];
  int h = blockIdx.y, n0 = blockIdx.x * 64;
  int tx = threadIdx.x & 63, ty = threadIdx.x >> 6;
  for (int i = ty; i < 64; i += 4)
    t[i][tx] = vb[((size_t)h*4096 + n0 + i)*64 + tx];
  __syncthreads();
  for (int i = ty; i < 64; i += 4)
    vtb[((size_t)h*64 + i)*4096 + n0 + tx] = t[tx][i];
}

// ---------------- fused attention: PERSISTENT single-pass (R18, proven) ----------------
__global__ __launch_bounds__(1024, 4) void k_attn3(
    const ushort* qb, const ushort* kbuf, const ushort* vtb,
    const float* adj, float* attn_out, ushort* az){
  __shared__ __align__(16) char smem[16*4096*2];   // 128 KB: pbf / pvp alias
  __shared__ float red[16][16];
  __shared__ float rsl[16];
  ushort* pbf = (ushort*)smem;                     // [16][4096], XOR-swizzled
  float (*pvp)[16][66] = (float(*)[16][66])smem;   // [16waves][16rows][64d+pad]

  int nb = blockIdx.x;                             // strip 0..255
  int n0 = nb * 16;
  int t = threadIdx.x;
  int wave = t >> 6, lane = t & 63, lr = lane & 15, lg = lane >> 4;

  for (int h = 0; h < 4; h++){
    const ushort* Qh = qb   + ((size_t)h*4096 + n0)*64;
    const ushort* Kh = kbuf + (size_t)h*4096*64;
    const ushort* Vt = vtb  + (size_t)h*64*4096;
    float* aout = attn_out + (size_t)h*4096*4096 + (size_t)n0*4096;

    bf16x8 afr0 = *(const bf16x8*)(Qh + (size_t)lr*64 +  0 + lg*8);
    bf16x8 afr1 = *(const bf16x8*)(Qh + (size_t)lr*64 + 32 + lg*8);

    const ushort* kp0 = Kh  + (size_t)(wave*16 + lr)*64 + lg*8;
    const float*  ap0 = adj + (size_t)(n0 + lg*4)*4096 + wave*16 + lr;
    float rsum[4] = {0.f, 0.f, 0.f, 0.f};
    #pragma unroll 2
    for (int ct = 0; ct < 16; ct++){
      const ushort* kp = kp0 + (size_t)ct*16384;   // 256 rows * 64
      const float*  ap = ap0 + ct*256;
      bf16x8 b0 = *(const bf16x8*)(kp);
      bf16x8 b1 = *(const bf16x8*)(kp + 32);
      float a0 = ap[0], a1 = ap[4096], a2 = ap[8192], a3 = ap[12288];
      f32x4 acc = {0.f, 0.f, 0.f, 0.f};
      acc = MFMA16(afr0, b0, acc);
      acc = MFMA16(afr1, b1, acc);
      float p0 = a0 * __expf(acc[0]);
      float p1 = a1 * __expf(acc[1]);
      float p2 = a2 * __expf(acc[2]);
      float p3 = a3 * __expf(acc[3]);
      rsum[0] += p0; rsum[1] += p1; rsum[2] += p2; rsum[3] += p3;
      int col = ct*256 + wave*16 + lr;
      float p4[4] = {p0, p1, p2, p3};
      #pragma unroll
      for (int r = 0; r < 4; r++){
        int row = lg*4 + r;
        pbf[row*4096 + (col ^ ((row & 7) << 3))] = f2bf(p4[r]);
      }
    }
    #pragma unroll
    for (int m = 1; m <= 8; m <<= 1){
      #pragma unroll
      for (int r = 0; r < 4; r++) rsum[r] += __shfl_xor(rsum[r], m, 64);
    }
    if (lr == 0){
      #pragma unroll
      for (int r = 0; r < 4; r++) red[wave][lg*4 + r] = rsum[r];
    }
    __syncthreads();
    if (t < 16){
      float s = 0.f;
      #pragma unroll
      for (int w2 = 0; w2 < 16; w2++) s += red[w2][t];
      rsl[t] = 1.f / s;
    }
    __syncthreads();

    {
      int row = wave;
      float iv = rsl[row];
      int swz = (row & 7) << 3;
      #pragma unroll 2
      for (int q = 0; q < 16; q++){
        int c = q*256 + lane*4;
        const ushort* src = &pbf[row*4096 + (c ^ swz)];
        ushort s4[4];
        *(uint2*)s4 = *(const uint2*)src;
        f32x4 ov = {bf2f(s4[0])*iv, bf2f(s4[1])*iv, bf2f(s4[2])*iv, bf2f(s4[3])*iv};
        __builtin_nontemporal_store(ov, (f32x4*)(aout + (size_t)row*4096 + c));
      }
    }

    f32x4 pacc[4];
    #pragma unroll
    for (int d = 0; d < 4; d++) pacc[d] = (f32x4){0.f,0.f,0.f,0.f};
    #pragma unroll
    for (int ks = 0; ks < 8; ks++){
      int kb2 = wave*256 + ks*32;
      bf16x8 pa = *(const bf16x8*)&pbf[lr*4096 + ((kb2 + lg*8) ^ ((lr & 7) << 3))];
      #pragma unroll
      for (int df = 0; df < 4; df++){
        bf16x8 v8 = *(const bf16x8*)(Vt + (size_t)(df*16 + lr)*4096 + kb2 + lg*8);
        pacc[df] = MFMA16(pa, v8, pacc[df]);
      }
    }

    __syncthreads();
    #pragma unroll
    for (int df = 0; df < 4; df++)
      #pragma unroll
      for (int r = 0; r < 4; r++)
        pvp[wave][lg*4 + r][df*16 + lr] = pacc[df][r];
    __syncthreads();
    {
      int row = t >> 6;
      int d   = t & 63;
      float s = 0.f;
      #pragma unroll
      for (int w2 = 0; w2 < 16; w2++) s += pvp[w2][row][d];
      s *= rsl[row];
      az[(size_t)(n0 + row)*512 + h*64 + d] = f2bf(s);
    }
    __syncthreads();
  }
}

// ---------------- GEMM v2: global_load_lds + pre-swizzled source ----------------
// C = act(A @ Bt^T + bias [+ res]). A bf16 [M][K], Bt bf16 [N][K].
// 64x64 tile, BK=32. Staging: 1 global_load_lds(16B)/thread/operand into
// LINEAR [64][32] LDS; source col pre-swizzled 8*((t&3)^(row&3)); frag reads
// apply the same involution -> conflict-free without padding (m173/m104).
__global__ __launch_bounds__(256) void k_gemm(
    const ushort* A, const ushort* Bt, const float* bias,
    const float* res, float* outf, ushort* outb,
    int M, int N, int K, int mode){
  __shared__ __align__(16) ushort la[64*32];
  __shared__ __align__(16) ushort lb[64*32];
  int mb = blockIdx.x * 64, nb = blockIdx.y * 64;
  int t = threadIdx.x;
  int wave = t >> 6, lane = t & 63, lr = lane & 15, lg = lane >> 4;
  int wm = (wave >> 1) * 32, wn = (wave & 1) * 32;
  f32x4 acc[2][2];
  #pragma unroll
  for (int i = 0; i < 2; i++)
    #pragma unroll
    for (int j = 0; j < 2; j++) acc[i][j] = (f32x4){0.f,0.f,0.f,0.f};

  int srow = t >> 2;                        // staging row 0..63
  int scol = 8 * ((t & 3) ^ (srow & 3));    // pre-swizzled source column
  const ushort* Ag = A  + (size_t)(mb + srow)*K + scol;
  const ushort* Bg = Bt + (size_t)(nb + srow)*K + scol;
  ushort* ldsA = la + (size_t)wave*512;     // wave-uniform base; lane*16B linear
  ushort* ldsB = lb + (size_t)wave*512;

  for (int k0 = 0; k0 < K; k0 += 32){
    __builtin_amdgcn_global_load_lds((const __attribute__((address_space(1))) unsigned int*)(Ag + k0),
                                     (__attribute__((address_space(3))) unsigned int*)ldsA, 16, 0, 0);
    __builtin_amdgcn_global_load_lds((const __attribute__((address_space(1))) unsigned int*)(Bg + k0),
                                     (__attribute__((address_space(3))) unsigned int*)ldsB, 16, 0, 0);
    __syncthreads();
    #pragma unroll
    for (int i = 0; i < 2; i++){
      int ar = wm + i*16 + lr;
      bf16x8 af = *(const bf16x8*)&la[ar*32 + ((lg ^ (ar & 3)) * 8)];
      #pragma unroll
      for (int j = 0; j < 2; j++){
        int br = wn + j*16 + lr;
        bf16x8 bfg = *(const bf16x8*)&lb[br*32 + ((lg ^ (br & 3)) * 8)];
        acc[i][j] = MFMA16(af, bfg, acc[i][j]);
      }
    }
    __syncthreads();
  }

  #pragma unroll
  for (int i = 0; i < 2; i++)
    #pragma unroll
    for (int j = 0; j < 2; j++){
      int col = nb + wn + j*16 + lr;
      float bv = bias[col];
      #pragma unroll
      for (int r = 0; r < 4; r++){
        int row = mb + wm + i*16 + lg*4 + r;
        float v = acc[i][j][r] + bv;
        if (mode == 0){
          if (res) v += res[(size_t)row*N + col];
          outf[(size_t)row*N + col] = v;
        } else {
          float gl = 0.5f * v * (1.f + erff(v * 0.70710678118f));
          outb[(size_t)row*N + col] = f2bf(gl);
        }
      }
    }
}

// ---------------- LayerNorm over 256 cols, wave per row ----------------
__global__ __launch_bounds__(256) void k_ln(const float* X, const float* g, const float* b,
                                            float* outf, ushort* outb){
  int row = blockIdx.x * 4 + (threadIdx.x >> 6);
  int lane = threadIdx.x & 63;
  const float* xr = X + (size_t)row*256;
  f32x4 v = *(const f32x4*)(xr + lane*4);
  float s = v[0] + v[1] + v[2] + v[3];
  #pragma unroll
  for (int m = 32; m >= 1; m >>= 1) s += __shfl_xor(s, m, 64);
  float mean = s * (1.f/256.f);
  float d0[4]; float sq = 0.f;
  #pragma unroll
  for (int e = 0; e < 4; e++){ d0[e] = v[e] - mean; sq += d0[e]*d0[e]; }
  #pragma unroll
  for (int m = 32; m >= 1; m >>= 1) sq += __shfl_xor(sq, m, 64);
  float rstd = rsqrtf(sq * (1.f/256.f) + 1e-5f);
  float o[4];
  #pragma unroll
  for (int e = 0; e < 4; e++)
    o[e] = d0[e]*rstd*g[lane*4 + e] + b[lane*4 + e];
  if (outf){
    f32x4 ov = {o[0], o[1], o[2], o[3]};
    *(f32x4*)(outf + (size_t)row*256 + lane*4) = ov;
  }
  if (outb){
    union { ushort u[4]; uint2 q; } pk;
    #pragma unroll
    for (int e = 0; e < 4; e++) pk.u[e] = f2bf(o[e]);
    *(uint2*)(outb + (size_t)row*256 + lane*4) = pk.q;
  }
}

// ---------------- launch ----------------
extern "C" void kernel_launch(void* const* d_in, const int* in_sizes, int n_in,
                              void* d_out, int out_size, void* d_ws, size_t ws_size,
                              hipStream_t stream){
  const float* Z    = (const float*)d_in[0];
  const float* Zg   = (const float*)d_in[1];
  const float* Zc   = (const float*)d_in[2];
  const float* adj  = (const float*)d_in[3];
  const float* Wq   = (const float*)d_in[4];
  const float* bq   = (const float*)d_in[5];
  const float* Wk   = (const float*)d_in[6];
  const float* bk   = (const float*)d_in[7];
  const float* Wv   = (const float*)d_in[8];
  const float* bv   = (const float*)d_in[9];
  const float* Wo   = (const float*)d_in[10];
  const float* bo   = (const float*)d_in[11];
  const float* Wr   = (const float*)d_in[12];
  const float* br   = (const float*)d_in[13];
  const float* ln1g = (const float*)d_in[14];
  const float* ln1b = (const float*)d_in[15];
  const float* ln2g = (const float*)d_in[16];
  const float* ln2b = (const float*)d_in[17];
  const float* f1w  = (const float*)d_in[18];
  const float* f1b  = (const float*)d_in[19];
  const float* f2w  = (const float*)d_in[20];
  const float* f2b  = (const float*)d_in[21];
  const float* f3w  = (const float*)d_in[22];
  const float* f3b  = (const float*)d_in[23];

  // OUTPUTS: f32 out [4096*256] then f32 attn [4*4096*4096]
  float* outF  = (float*)d_out;
  float* attnF = outF + (size_t)4096*256;

  const size_t MB = 1048576;
  char* w = (char*)d_ws;
  ushort* qb    = (ushort*)(w + 0*MB);      // 2 MB, dead after k_attn3
  ushort* kbuf  = (ushort*)(w + 2*MB);      // 2 MB, dead after k_attn3
  ushort* vtb   = (ushort*)(w + 4*MB);      // 2 MB, dead after k_attn3
  ushort* vb    = (ushort*)(w + 6*MB);      // 2 MB, dead after k_vtrans
  ushort* h1    = (ushort*)(w + 0*MB);      // 8 MB, written after k_attn3
  ushort* AZ    = (ushort*)(w + 8*MB);      // 4 MB, dead after gemm1
  ushort* h2    = (ushort*)(w + 8*MB);      // 4 MB, written after gemm1
  ushort* BoR   = (ushort*)(w + 12*MB);                 // 256 KB [256][512]
  float*  biasOR= (float*)(w + 12*MB + 262144);         // 1 KB
  ushort* f1T   = (ushort*)(w + 13*MB);     // 512 KB [1024][256]
  ushort* f2T   = (ushort*)(w + 13*MB + 524288);  // 1 MB [512][1024]
  ushort* f3T   = (ushort*)(w + 14*MB + 524288);  // 256 KB [256][512]
  float*  X1    = (float*)(w + 15*MB);      // 4 MB
  float*  yf    = (float*)(w + 19*MB);      // 4 MB
  ushort* yb    = (ushort*)(w + 23*MB);     // 2 MB -> peak 25 MB

  // prep
  k_cvtZ<<<4096, 256, 0, stream>>>(Z, AZ);
  k_transpose<<<dim3(8,  8), 256, 0, stream>>>(Wo,  BoR,  256,  256, 512,   0);
  k_transpose<<<dim3(8,  8), 256, 0, stream>>>(Wr,  BoR,  256,  256, 512, 256);
  k_transpose<<<dim3(8, 32), 256, 0, stream>>>(f1w, f1T,  256, 1024, 256,   0);
  k_transpose<<<dim3(32,16), 256, 0, stream>>>(f2w, f2T, 1024,  512, 1024,  0);
  k_transpose<<<dim3(16, 8), 256, 0, stream>>>(f3w, f3T,  512,  256, 512,   0);
  k_biasor<<<1, 256, 0, stream>>>(bo, br, biasOR);

  // QKV + V transpose
  k_qkv<<<256, 256, 0, stream>>>(Zg, Zc, Wq, bq, Wk, bk, Wv, bv, qb, kbuf, vb);
  k_vtrans<<<dim3(64, 4), 256, 0, stream>>>(vb, vtb);

  // fused attention (persistent): normalized attn (f32, NT) + attended AZ (bf16)
  k_attn3<<<256, 1024, 0, stream>>>(qb, kbuf, vtb, adj, attnF, AZ);

  // X1 = [attended|Z] @ [Wo;Wr]^T + (bo+br)
  k_gemm<<<dim3(64, 4), 256, 0, stream>>>(AZ, BoR, biasOR, nullptr, X1, nullptr,
                                          4096, 256, 512, 0);
  k_ln<<<1024, 256, 0, stream>>>(X1, ln1g, ln1b, yf, yb);

  // FFN
  k_gemm<<<dim3(64,16), 256, 0, stream>>>(yb, f1T, f1b, nullptr, nullptr, h1,
                                          4096, 1024, 256, 1);
  k_gemm<<<dim3(64, 8), 256, 0, stream>>>(h1, f2T, f2b, nullptr, nullptr, h2,
                                          4096, 512, 1024, 1);
  k_gemm<<<dim3(64, 4), 256, 0, stream>>>(h2, f3T, f3b, yf, X1, nullptr,
                                          4096, 256, 512, 0);
  k_ln<<<1024, 256, 0, stream>>>(X1, ln2g, ln2b, outF, nullptr);
}